// Round 1
// baseline (34046.799 us; speedup 1.0000x reference)
//
#include <hip/hip_runtime.h>
#include <stdint.h>

typedef unsigned short u16;
typedef short bf16x8 __attribute__((ext_vector_type(8)));
typedef float f32x4  __attribute__((ext_vector_type(4)));
typedef unsigned short u16x8 __attribute__((ext_vector_type(8)));

__device__ __forceinline__ u16 f2bf(float f) {
  uint32_t u = __float_as_uint(f);
  return (u16)((u + 0x7FFFu + ((u >> 16) & 1u)) >> 16);
}
__device__ __forceinline__ float fsig(float x) {
  x = fminf(fmaxf(x, -30.f), 30.f);
  return __builtin_amdgcn_rcpf(1.f + __builtin_amdgcn_exp2f(-1.44269504088896f * x));
}
__device__ __forceinline__ float ftanhf(float x) {
  x = fminf(fmaxf(x, -10.f), 10.f);
  float e = __builtin_amdgcn_exp2f(2.88539008177793f * x);
  return (e - 1.f) * __builtin_amdgcn_rcpf(e + 1.f);
}

__device__ __forceinline__ void group_wait(const int* flags, int target) {
  if (threadIdx.x < 32) {
    int spins = 0;
    while (__hip_atomic_load(&flags[threadIdx.x], __ATOMIC_RELAXED, __HIP_MEMORY_SCOPE_AGENT) < target) {
      __builtin_amdgcn_s_sleep(1);
      if (++spins > 200000) break;   // bounded: broken sync -> wrong answer, not a hang
    }
  }
  __syncthreads();
  __builtin_amdgcn_fence(__ATOMIC_ACQUIRE, "agent");
}

// ---------------------------------------------------------------------------
// prep: f32 weights -> bf16 MFMA fragment layout, gate-permuted columns.
// n' = 4*unit + gate  =>  original column = gate*512 + unit.
// frag element (ntg,kt,lane,e): k = kt*32 + (lane>>4)*8 + e ; col = perm(ntg*16 + (lane&15))
// ---------------------------------------------------------------------------
__global__ void prep_kernel(const float* __restrict__ Wf, const float* __restrict__ Uf, const float* __restrict__ bf,
                            const float* __restrict__ Wb, const float* __restrict__ Ub, const float* __restrict__ bb,
                            const float* __restrict__ Wd, const float* __restrict__ Ud, const float* __restrict__ bd,
                            const float* __restrict__ Wo,
                            u16* __restrict__ encF, u16* __restrict__ encB,
                            u16* __restrict__ udF, u16* __restrict__ wdF, u16* __restrict__ woF,
                            float* __restrict__ biasF, float* __restrict__ biasB, float* __restrict__ biasD,
                            int* __restrict__ flagsAll)
{
  constexpr int NC_ENC = 128 * 24 * 64;     // 196608 chunks per direction
  constexpr int NC_UD  = 128 * 16 * 64;     // 131072
  constexpr int NC_WD  = 128 * 32 * 64;     // 262144
  constexpr int NC_WO  = 16 * 16 * 64;      // 16384
  constexpr int B1 = 2 * NC_ENC;            // end enc
  constexpr int B2 = B1 + NC_UD;            // end ud
  constexpr int B3 = B2 + NC_WD;            // end wd
  constexpr int B4 = B3 + NC_WO;            // end wo
  constexpr int B5 = B4 + 768;              // end bias (3 x 2048/8)
  constexpr int TOTAL = B5 + 64;            // 512 flag ints / 8

  for (int idx = blockIdx.x * 256 + threadIdx.x; idx < TOTAL; idx += gridDim.x * 256) {
    if (idx < B1) {
      int d = idx / NC_ENC;
      int r = idx - d * NC_ENC;
      int ntg = r / 1536;
      int rem = r - ntg * 1536;
      int kt = rem >> 6, lane = rem & 63;
      int np = ntg * 16 + (lane & 15);
      int col = (np & 3) * 512 + (np >> 2);
      int kb = kt * 32 + (lane >> 4) * 8;
      const float* W = d ? Wb : Wf;
      const float* U = d ? Ub : Uf;
      u16* dst = (d ? encB : encF) + (size_t)r * 8;
      if (kb < 256) {
        const float* s = W + (size_t)kb * 2048 + col;
#pragma unroll
        for (int e = 0; e < 8; ++e) dst[e] = f2bf(s[(size_t)e * 2048]);
      } else {
        const float* s = U + (size_t)(kb - 256) * 2048 + col;
#pragma unroll
        for (int e = 0; e < 8; ++e) dst[e] = f2bf(s[(size_t)e * 2048]);
      }
    } else if (idx < B2) {
      int r = idx - B1;
      int ntg = r / 1024;
      int rem = r - ntg * 1024;
      int kt = rem >> 6, lane = rem & 63;
      int np = ntg * 16 + (lane & 15);
      int col = (np & 3) * 512 + (np >> 2);
      int kb = kt * 32 + (lane >> 4) * 8;
      const float* s = Ud + (size_t)kb * 2048 + col;
      u16* dst = udF + (size_t)r * 8;
#pragma unroll
      for (int e = 0; e < 8; ++e) dst[e] = f2bf(s[(size_t)e * 2048]);
    } else if (idx < B3) {
      int r = idx - B2;
      int ntg = r / 2048;
      int rem = r - ntg * 2048;
      int kt = rem >> 6, lane = rem & 63;
      int np = ntg * 16 + (lane & 15);
      int col = (np & 3) * 512 + (np >> 2);
      int kb = kt * 32 + (lane >> 4) * 8;
      const float* s = Wd + (size_t)kb * 2048 + col;
      u16* dst = wdF + (size_t)r * 8;
#pragma unroll
      for (int e = 0; e < 8; ++e) dst[e] = f2bf(s[(size_t)e * 2048]);
    } else if (idx < B4) {
      int r = idx - B3;
      int nt = r / 1024;
      int rem = r - nt * 1024;
      int kt = rem >> 6, lane = rem & 63;
      int col = nt * 16 + (lane & 15);            // natural order for output dense
      int kb = kt * 32 + (lane >> 4) * 8;
      const float* s = Wo + (size_t)kb * 256 + col;
      u16* dst = woF + (size_t)r * 8;
#pragma unroll
      for (int e = 0; e < 8; ++e) dst[e] = f2bf(s[(size_t)e * 256]);
    } else if (idx < B5) {
      int r = idx - B4;
      int which = r >> 8;
      int j0 = (r & 255) * 8;
      const float* src = (which == 0) ? bf : (which == 1) ? bb : bd;
      float* dstb = (which == 0) ? biasF : (which == 1) ? biasB : biasD;
#pragma unroll
      for (int e = 0; e < 8; ++e) {
        int np = j0 + e;
        dstb[np] = src[(np & 3) * 512 + (np >> 2)];
      }
    } else {
      int r = idx - B5;
#pragma unroll
      for (int e = 0; e < 8; ++e) flagsAll[r * 8 + e] = 0;
    }
  }
}

// ---------------------------------------------------------------------------
// encoder: 8 groups (dir = g>>2, rows = (g&3)*32 .. +31), 32 WGs/group.
// WG = 256 thr (4 waves); wave w owns 16 gate-columns (nt=w), i.e. 4 hidden
// units; B-fragments live in 96 VGPRs. A = [x_t | h_{s-1}] staged to LDS bf16.
// ---------------------------------------------------------------------------
__global__ __launch_bounds__(256, 1) void enc_kernel(
    const float* __restrict__ x,
    const u16* __restrict__ encF, const u16* __restrict__ encB,
    const float* __restrict__ biasF, const float* __restrict__ biasB,
    float* __restrict__ latent, u16* __restrict__ hbuf, int* __restrict__ flags)
{
  const int bid = blockIdx.x;
  const int g   = bid & 7;
  const int wgi = bid >> 3;
  const int dir = g >> 2;
  const int rowBase = (g & 3) * 32;
  const int tid = threadIdx.x;
  const int lane = tid & 63;
  const int wave = tid >> 6;
  const int l15 = lane & 15;
  const int lk  = lane >> 4;

  __shared__ __attribute__((aligned(16))) u16   Alds[32][776];
  __shared__ __attribute__((aligned(16))) float zlds[4][16][20];

  const u16* fragBase = (dir ? encB : encF) + (size_t)wgi * 49152 + (size_t)wave * 12288 + (size_t)lane * 8;
  bf16x8 Breg[24];
#pragma unroll
  for (int kt = 0; kt < 24; ++kt)
    Breg[kt] = *(const bf16x8*)(fragBase + kt * 512);

  const float* bias = dir ? biasB : biasF;
  const float bias_r = bias[wgi * 64 + wave * 16 + l15];

  u16* myH = hbuf + (size_t)g * (2 * 32 * 512);
  int* myFlags = flags + g * 32;
  const int uB = wgi * 16 + wave * 4 + lk;

  float c0 = 0.f, c1 = 0.f;

  for (int s = 0; s < 1024; ++s) {
    const int t = dir ? (1023 - s) : s;

    if (s > 0) {
      group_wait(myFlags, s);
      const u16* hs = myH + ((s - 1) & 1) * (32 * 512);
#pragma unroll
      for (int c = 0; c < 8; ++c) {
        int cc = tid + c * 256;
        int rr = cc >> 6;
        int col = (cc & 63) * 8;
        *(uint4*)&Alds[rr][256 + col] = *(const uint4*)&hs[rr * 512 + col];
      }
    } else {
      __syncthreads();
    }

#pragma unroll
    for (int c = 0; c < 4; ++c) {
      int cc = tid + c * 256;
      int rr = cc >> 5;
      int col = (cc & 31) * 8;
      const float* xp = x + ((size_t)(rowBase + rr) * 1024 + t) * 256 + col;
      float4 v0 = *(const float4*)xp;
      float4 v1 = *(const float4*)(xp + 4);
      u16x8 tv;
      tv[0] = f2bf(v0.x); tv[1] = f2bf(v0.y); tv[2] = f2bf(v0.z); tv[3] = f2bf(v0.w);
      tv[4] = f2bf(v1.x); tv[5] = f2bf(v1.y); tv[6] = f2bf(v1.z); tv[7] = f2bf(v1.w);
      *(u16x8*)&Alds[rr][col] = tv;
    }
    __syncthreads();

    f32x4 acc0 = {bias_r, bias_r, bias_r, bias_r};
    f32x4 acc1 = acc0;
    if (s > 0) {
#pragma unroll
      for (int kt = 0; kt < 24; ++kt) {
        bf16x8 a0 = *(const bf16x8*)&Alds[l15][kt * 32 + lk * 8];
        bf16x8 a1 = *(const bf16x8*)&Alds[16 + l15][kt * 32 + lk * 8];
        acc0 = __builtin_amdgcn_mfma_f32_16x16x32_bf16(a0, Breg[kt], acc0, 0, 0, 0);
        acc1 = __builtin_amdgcn_mfma_f32_16x16x32_bf16(a1, Breg[kt], acc1, 0, 0, 0);
      }
    } else {
#pragma unroll
      for (int kt = 0; kt < 8; ++kt) {          // s==0: h=0, only x@W part
        bf16x8 a0 = *(const bf16x8*)&Alds[l15][kt * 32 + lk * 8];
        bf16x8 a1 = *(const bf16x8*)&Alds[16 + l15][kt * 32 + lk * 8];
        acc0 = __builtin_amdgcn_mfma_f32_16x16x32_bf16(a0, Breg[kt], acc0, 0, 0, 0);
        acc1 = __builtin_amdgcn_mfma_f32_16x16x32_bf16(a1, Breg[kt], acc1, 0, 0, 0);
      }
    }

    u16* hw = myH + (s & 1) * (32 * 512);
    {
#pragma unroll
      for (int r = 0; r < 4; ++r) zlds[wave][lk * 4 + r][l15] = acc0[r];
      asm volatile("s_waitcnt lgkmcnt(0)" ::: "memory");
      float4 gv = *(const float4*)&zlds[wave][l15][lk * 4];
      float iv = fsig(gv.x), fv = fsig(gv.y), gg = ftanhf(gv.z), ov = fsig(gv.w);
      c0 = fv * c0 + iv * gg;
      float hv = ov * ftanhf(c0);
      hw[l15 * 512 + uB] = f2bf(hv);
      if (s == 1023) latent[(size_t)(rowBase + l15) * 1024 + dir * 512 + uB] = hv;
    }
    {
#pragma unroll
      for (int r = 0; r < 4; ++r) zlds[wave][lk * 4 + r][l15] = acc1[r];
      asm volatile("s_waitcnt lgkmcnt(0)" ::: "memory");
      float4 gv = *(const float4*)&zlds[wave][l15][lk * 4];
      float iv = fsig(gv.x), fv = fsig(gv.y), gg = ftanhf(gv.z), ov = fsig(gv.w);
      c1 = fv * c1 + iv * gg;
      float hv = ov * ftanhf(c1);
      hw[(16 + l15) * 512 + uB] = f2bf(hv);
      if (s == 1023) latent[(size_t)(rowBase + 16 + l15) * 1024 + dir * 512 + uB] = hv;
    }

    __syncthreads();                       // drains vmcnt before release
    if (tid == 0 && s < 1023) {
      __builtin_amdgcn_fence(__ATOMIC_RELEASE, "agent");
      __hip_atomic_store(&myFlags[wgi], s + 1, __ATOMIC_RELAXED, __HIP_MEMORY_SCOPE_AGENT);
    }
  }
}

// ---------------------------------------------------------------------------
// decoder: 8 groups x 16 rows, 32 WGs/group. xwd = latent@Wd+bd held in regs
// (time-invariant). Output Dense fused: at step t, after staging h_{t-1},
// WGs wgi<16 (wave 0) emit out[:, t-1, :].
// ---------------------------------------------------------------------------
__global__ __launch_bounds__(256, 1) void dec_kernel(
    const float* __restrict__ latent,
    const u16* __restrict__ udF, const u16* __restrict__ wdF, const u16* __restrict__ woF,
    const float* __restrict__ biasD, const float* __restrict__ bo,
    float* __restrict__ out, u16* __restrict__ hbuf, int* __restrict__ flags)
{
  const int bid = blockIdx.x;
  const int g   = bid & 7;
  const int wgi = bid >> 3;
  const int rowBase = g * 16;
  const int tid = threadIdx.x;
  const int lane = tid & 63;
  const int wave = tid >> 6;
  const int l15 = lane & 15;
  const int lk  = lane >> 4;

  __shared__ __attribute__((aligned(16))) u16   Llds[16][1032];
  __shared__ __attribute__((aligned(16))) u16   Alds[16][520];
  __shared__ __attribute__((aligned(16))) float zlds[4][16][20];

#pragma unroll
  for (int c = 0; c < 8; ++c) {
    int cc = tid + c * 256;
    int rr = cc >> 7;
    int col = (cc & 127) * 8;
    const float* lp = latent + (size_t)(rowBase + rr) * 1024 + col;
    float4 v0 = *(const float4*)lp;
    float4 v1 = *(const float4*)(lp + 4);
    u16x8 tv;
    tv[0] = f2bf(v0.x); tv[1] = f2bf(v0.y); tv[2] = f2bf(v0.z); tv[3] = f2bf(v0.w);
    tv[4] = f2bf(v1.x); tv[5] = f2bf(v1.y); tv[6] = f2bf(v1.z); tv[7] = f2bf(v1.w);
    *(u16x8*)&Llds[rr][col] = tv;
  }
  __syncthreads();

  const float bd_r = biasD[wgi * 64 + wave * 16 + l15];
  f32x4 xwd = {bd_r, bd_r, bd_r, bd_r};
  {
    const u16* wf = wdF + (size_t)(wgi * 4 + wave) * 16384 + (size_t)lane * 8;
#pragma unroll
    for (int kt = 0; kt < 32; ++kt) {
      bf16x8 b = *(const bf16x8*)(wf + kt * 512);
      bf16x8 a = *(const bf16x8*)&Llds[l15][kt * 32 + lk * 8];
      xwd = __builtin_amdgcn_mfma_f32_16x16x32_bf16(a, b, xwd, 0, 0, 0);
    }
  }

  const u16* uf = udF + (size_t)(wgi * 4 + wave) * 8192 + (size_t)lane * 8;
  bf16x8 Bu[16];
#pragma unroll
  for (int kt = 0; kt < 16; ++kt) Bu[kt] = *(const bf16x8*)(uf + kt * 512);

  const bool doDense = (wgi < 16) && (wave == 0);
  bf16x8 Bo[16];
  if (doDense) {
    const u16* wof = woF + (size_t)wgi * 8192 + (size_t)lane * 8;
#pragma unroll
    for (int kt = 0; kt < 16; ++kt) Bo[kt] = *(const bf16x8*)(wof + kt * 512);
  }
  const float bo_r = (wgi < 16) ? bo[wgi * 16 + l15] : 0.f;

  u16* myH = hbuf + (size_t)g * (2 * 16 * 512);
  int* myFlags = flags + g * 32;
  const int uB = wgi * 16 + wave * 4 + lk;
  float creg = 0.f;

  for (int t = 0; t < 1024; ++t) {
    if (t > 0) {
      group_wait(myFlags, t);
      const u16* hs = myH + ((t - 1) & 1) * (16 * 512);
#pragma unroll
      for (int c = 0; c < 4; ++c) {
        int cc = tid + c * 256;
        int rr = cc >> 6;
        int col = (cc & 63) * 8;
        *(uint4*)&Alds[rr][col] = *(const uint4*)&hs[rr * 512 + col];
      }
      __syncthreads();
      if (doDense) {
        f32x4 od = {bo_r, bo_r, bo_r, bo_r};
#pragma unroll
        for (int kt = 0; kt < 16; ++kt) {
          bf16x8 a = *(const bf16x8*)&Alds[l15][kt * 32 + lk * 8];
          od = __builtin_amdgcn_mfma_f32_16x16x32_bf16(a, Bo[kt], od, 0, 0, 0);
        }
#pragma unroll
        for (int r = 0; r < 4; ++r)
          out[((size_t)(rowBase + lk * 4 + r) * 1024 + (t - 1)) * 256 + wgi * 16 + l15] = od[r];
      }
    }

    f32x4 acc = xwd;
    if (t > 0) {
#pragma unroll
      for (int kt = 0; kt < 16; ++kt) {
        bf16x8 a = *(const bf16x8*)&Alds[l15][kt * 32 + lk * 8];
        acc = __builtin_amdgcn_mfma_f32_16x16x32_bf16(a, Bu[kt], acc, 0, 0, 0);
      }
    }

    {
#pragma unroll
      for (int r = 0; r < 4; ++r) zlds[wave][lk * 4 + r][l15] = acc[r];
      asm volatile("s_waitcnt lgkmcnt(0)" ::: "memory");
      float4 gv = *(const float4*)&zlds[wave][l15][lk * 4];
      float iv = fsig(gv.x), fv = fsig(gv.y), gg = ftanhf(gv.z), ov = fsig(gv.w);
      creg = fv * creg + iv * gg;
      float hv = ov * ftanhf(creg);
      myH[(t & 1) * (16 * 512) + l15 * 512 + uB] = f2bf(hv);
    }

    __syncthreads();
    if (tid == 0) {
      __builtin_amdgcn_fence(__ATOMIC_RELEASE, "agent");
      __hip_atomic_store(&myFlags[wgi], t + 1, __ATOMIC_RELAXED, __HIP_MEMORY_SCOPE_AGENT);
    }
  }

  // final output column (t = 1023)
  group_wait(myFlags, 1024);
  {
    const u16* hs = myH + (16 * 512);     // buf 1 = h_{1023}
#pragma unroll
    for (int c = 0; c < 4; ++c) {
      int cc = tid + c * 256;
      int rr = cc >> 6;
      int col = (cc & 63) * 8;
      *(uint4*)&Alds[rr][col] = *(const uint4*)&hs[rr * 512 + col];
    }
    __syncthreads();
    if (doDense) {
      f32x4 od = {bo_r, bo_r, bo_r, bo_r};
#pragma unroll
      for (int kt = 0; kt < 16; ++kt) {
        bf16x8 a = *(const bf16x8*)&Alds[l15][kt * 32 + lk * 8];
        od = __builtin_amdgcn_mfma_f32_16x16x32_bf16(a, Bo[kt], od, 0, 0, 0);
      }
#pragma unroll
      for (int r = 0; r < 4; ++r)
        out[((size_t)(rowBase + lk * 4 + r) * 1024 + 1023) * 256 + wgi * 16 + l15] = od[r];
    }
  }
}

// ---------------------------------------------------------------------------
extern "C" void kernel_launch(void* const* d_in, const int* in_sizes, int n_in,
                              void* d_out, int out_size, void* d_ws, size_t ws_size,
                              hipStream_t stream)
{
  const float* x  = (const float*)d_in[0];
  const float* Wf = (const float*)d_in[1];
  const float* Uf = (const float*)d_in[2];
  const float* bf = (const float*)d_in[3];
  const float* Wb = (const float*)d_in[4];
  const float* Ub = (const float*)d_in[5];
  const float* bb = (const float*)d_in[6];
  const float* Wd = (const float*)d_in[7];
  const float* Ud = (const float*)d_in[8];
  const float* bd = (const float*)d_in[9];
  const float* Wo = (const float*)d_in[10];
  const float* bo = (const float*)d_in[11];

  if (ws_size < 14182400) return;   // workspace layout below needs ~14.2 MB

  char* ws = (char*)d_ws;
  u16*  encF   = (u16*)(ws + 0);
  u16*  encB   = (u16*)(ws + 3145728);
  u16*  udF    = (u16*)(ws + 6291456);
  u16*  wdF    = (u16*)(ws + 8388608);
  u16*  woF    = (u16*)(ws + 12582912);
  float* biasF = (float*)(ws + 12845056);
  float* biasB = (float*)(ws + 12853248);
  float* biasD = (float*)(ws + 12861440);
  float* latent= (float*)(ws + 12869632);
  u16*  hbufE  = (u16*)(ws + 13393920);
  u16*  hbufD  = (u16*)(ws + 13918208);
  int*  flagsE = (int*)(ws + 14180352);
  int*  flagsD = (int*)(ws + 14181376);   // contiguous with flagsE (512 ints zeroed by prep)

  prep_kernel<<<256, 256, 0, stream>>>(Wf, Uf, bf, Wb, Ub, bb, Wd, Ud, bd, Wo,
                                       encF, encB, udF, wdF, woF,
                                       biasF, biasB, biasD, flagsE);
  enc_kernel<<<256, 256, 0, stream>>>(x, encF, encB, biasF, biasB, latent, hbufE, flagsE);
  dec_kernel<<<256, 256, 0, stream>>>(latent, udF, wdF, woF, biasD, bo,
                                      (float*)d_out, hbufD, flagsD);
}

// Round 2
// 6172.668 us; speedup vs baseline: 5.5157x; 5.5157x over previous
//
#include <hip/hip_runtime.h>
#include <stdint.h>

typedef unsigned short u16;
typedef short bf16x8 __attribute__((ext_vector_type(8)));
typedef float f32x4  __attribute__((ext_vector_type(4)));
typedef unsigned short u16x8 __attribute__((ext_vector_type(8)));

__device__ __forceinline__ u16 f2bf(float f) {
  uint32_t u = __float_as_uint(f);
  return (u16)((u + 0x7FFFu + ((u >> 16) & 1u)) >> 16);
}
__device__ __forceinline__ float fsig(float x) {
  x = fminf(fmaxf(x, -30.f), 30.f);
  return __builtin_amdgcn_rcpf(1.f + __builtin_amdgcn_exp2f(-1.44269504088896f * x));
}
__device__ __forceinline__ float ftanhf(float x) {
  x = fminf(fmaxf(x, -10.f), 10.f);
  float e = __builtin_amdgcn_exp2f(2.88539008177793f * x);
  return (e - 1.f) * __builtin_amdgcn_rcpf(e + 1.f);
}

// Coherent (cross-XCD) flag ops: sc0 sc1 => bypass L1/L2, serialize at MALL.
__device__ __forceinline__ int flag_load(const int* p) {
  int v;
  asm volatile("global_load_dword %0, %1, off sc0 sc1\n\ts_waitcnt vmcnt(0)"
               : "=v"(v) : "v"(p) : "memory");
  return v;
}
__device__ __forceinline__ void flag_store(int* p, int v) {
  asm volatile("global_store_dword %0, %1, off sc0 sc1" :: "v"(p), "v"(v) : "memory");
}
__device__ __forceinline__ uint4 ld_coh_x4_issue(const u16* p) {  // NO waitcnt inside
  uint4 v;
  asm volatile("global_load_dwordx4 %0, %1, off sc0 sc1" : "=v"(v) : "v"(p) : "memory");
  return v;
}
__device__ __forceinline__ void st_coh_dword(const u16* p, uint32_t v) {
  asm volatile("global_store_dword %0, %1, off sc0 sc1" :: "v"(p), "v"(v) : "memory");
}
__device__ __forceinline__ void wait_vm0() {
  asm volatile("s_waitcnt vmcnt(0)" ::: "memory");
}

__device__ __forceinline__ void group_wait(const int* flags, int target) {
  if (threadIdx.x < 32) {
    const int* fp = &flags[threadIdx.x];
    int spins = 0;
    while (flag_load(fp) < target) {
      __builtin_amdgcn_s_sleep(1);
      if (++spins > 200000) break;   // bounded: broken sync -> wrong answer, not a hang
    }
  }
  __syncthreads();
}

// ---------------------------------------------------------------------------
// prep: f32 weights -> bf16 MFMA fragment layout, gate-permuted columns.
// n' = 4*unit + gate  =>  original column = gate*512 + unit.
// ---------------------------------------------------------------------------
__global__ void prep_kernel(const float* __restrict__ Wf, const float* __restrict__ Uf, const float* __restrict__ bf,
                            const float* __restrict__ Wb, const float* __restrict__ Ub, const float* __restrict__ bb,
                            const float* __restrict__ Wd, const float* __restrict__ Ud, const float* __restrict__ bd,
                            const float* __restrict__ Wo,
                            u16* __restrict__ encF, u16* __restrict__ encB,
                            u16* __restrict__ udF, u16* __restrict__ wdF, u16* __restrict__ woF,
                            float* __restrict__ biasF, float* __restrict__ biasB, float* __restrict__ biasD,
                            int* __restrict__ flagsAll)
{
  constexpr int NC_ENC = 128 * 24 * 64;
  constexpr int NC_UD  = 128 * 16 * 64;
  constexpr int NC_WD  = 128 * 32 * 64;
  constexpr int NC_WO  = 16 * 16 * 64;
  constexpr int B1 = 2 * NC_ENC;
  constexpr int B2 = B1 + NC_UD;
  constexpr int B3 = B2 + NC_WD;
  constexpr int B4 = B3 + NC_WO;
  constexpr int B5 = B4 + 768;
  constexpr int TOTAL = B5 + 64;

  for (int idx = blockIdx.x * 256 + threadIdx.x; idx < TOTAL; idx += gridDim.x * 256) {
    if (idx < B1) {
      int d = idx / NC_ENC;
      int r = idx - d * NC_ENC;
      int ntg = r / 1536;
      int rem = r - ntg * 1536;
      int kt = rem >> 6, lane = rem & 63;
      int np = ntg * 16 + (lane & 15);
      int col = (np & 3) * 512 + (np >> 2);
      int kb = kt * 32 + (lane >> 4) * 8;
      const float* W = d ? Wb : Wf;
      const float* U = d ? Ub : Uf;
      u16* dst = (d ? encB : encF) + (size_t)r * 8;
      if (kb < 256) {
        const float* s = W + (size_t)kb * 2048 + col;
#pragma unroll
        for (int e = 0; e < 8; ++e) dst[e] = f2bf(s[(size_t)e * 2048]);
      } else {
        const float* s = U + (size_t)(kb - 256) * 2048 + col;
#pragma unroll
        for (int e = 0; e < 8; ++e) dst[e] = f2bf(s[(size_t)e * 2048]);
      }
    } else if (idx < B2) {
      int r = idx - B1;
      int ntg = r / 1024;
      int rem = r - ntg * 1024;
      int kt = rem >> 6, lane = rem & 63;
      int np = ntg * 16 + (lane & 15);
      int col = (np & 3) * 512 + (np >> 2);
      int kb = kt * 32 + (lane >> 4) * 8;
      const float* s = Ud + (size_t)kb * 2048 + col;
      u16* dst = udF + (size_t)r * 8;
#pragma unroll
      for (int e = 0; e < 8; ++e) dst[e] = f2bf(s[(size_t)e * 2048]);
    } else if (idx < B3) {
      int r = idx - B2;
      int ntg = r / 2048;
      int rem = r - ntg * 2048;
      int kt = rem >> 6, lane = rem & 63;
      int np = ntg * 16 + (lane & 15);
      int col = (np & 3) * 512 + (np >> 2);
      int kb = kt * 32 + (lane >> 4) * 8;
      const float* s = Wd + (size_t)kb * 2048 + col;
      u16* dst = wdF + (size_t)r * 8;
#pragma unroll
      for (int e = 0; e < 8; ++e) dst[e] = f2bf(s[(size_t)e * 2048]);
    } else if (idx < B4) {
      int r = idx - B3;
      int nt = r / 1024;
      int rem = r - nt * 1024;
      int kt = rem >> 6, lane = rem & 63;
      int col = nt * 16 + (lane & 15);
      int kb = kt * 32 + (lane >> 4) * 8;
      const float* s = Wo + (size_t)kb * 256 + col;
      u16* dst = woF + (size_t)r * 8;
#pragma unroll
      for (int e = 0; e < 8; ++e) dst[e] = f2bf(s[(size_t)e * 256]);
    } else if (idx < B5) {
      int r = idx - B4;
      int which = r >> 8;
      int j0 = (r & 255) * 8;
      const float* src = (which == 0) ? bf : (which == 1) ? bb : bd;
      float* dstb = (which == 0) ? biasF : (which == 1) ? biasB : biasD;
#pragma unroll
      for (int e = 0; e < 8; ++e) {
        int np = j0 + e;
        dstb[np] = src[(np & 3) * 512 + (np >> 2)];
      }
    } else {
      int r = idx - B5;
#pragma unroll
      for (int e = 0; e < 8; ++e) flagsAll[r * 8 + e] = 0;
    }
  }
}

// ---------------------------------------------------------------------------
// encoder: 8 groups (dir = g>>2, rows = (g&3)*32..+31), 32 WGs/group, 1 WG/CU.
// Per step: stage x + x-part MFMA (off critical path) -> wait flag -> coherent
// h load (sc0sc1, no cache flush) -> h-part MFMA -> act -> coalesced coherent
// h store -> vmcnt drain -> flag release.
// ---------------------------------------------------------------------------
__global__ __launch_bounds__(256, 1) void enc_kernel(
    const float* __restrict__ x,
    const u16* __restrict__ encF, const u16* __restrict__ encB,
    const float* __restrict__ biasF, const float* __restrict__ biasB,
    float* __restrict__ latent, u16* __restrict__ hbuf, int* __restrict__ flags)
{
  const int bid = blockIdx.x;
  const int g   = bid & 7;
  const int wgi = bid >> 3;
  const int dir = g >> 2;
  const int rowBase = (g & 3) * 32;
  const int tid = threadIdx.x;
  const int lane = tid & 63;
  const int wave = tid >> 6;
  const int l15 = lane & 15;
  const int lk  = lane >> 4;

  __shared__ __attribute__((aligned(16))) u16   Alds[32][776];
  __shared__ __attribute__((aligned(16))) float zlds[4][16][20];
  __shared__ __attribute__((aligned(16))) u16   hlds[32][16];

  const u16* fragBase = (dir ? encB : encF) + (size_t)wgi * 49152 + (size_t)wave * 12288 + (size_t)lane * 8;
  bf16x8 Breg[24];
#pragma unroll
  for (int kt = 0; kt < 24; ++kt)
    Breg[kt] = *(const bf16x8*)(fragBase + kt * 512);

  const float* bias = dir ? biasB : biasF;
  const float bias_r = bias[wgi * 64 + wave * 16 + l15];

  u16* myH = hbuf + (size_t)g * (2 * 32 * 512);
  int* myFlags = flags + g * 32;
  const int uB = wgi * 16 + wave * 4 + lk;

  float c0 = 0.f, c1 = 0.f;

  for (int s = 0; s < 1024; ++s) {
    const int t = dir ? (1023 - s) : s;

    // ---- stage x_t (no cross-WG dependency) ----
#pragma unroll
    for (int c = 0; c < 4; ++c) {
      int cc = tid + c * 256;
      int rr = cc >> 5;
      int col = (cc & 31) * 8;
      const float* xp = x + ((size_t)(rowBase + rr) * 1024 + t) * 256 + col;
      float4 v0 = *(const float4*)xp;
      float4 v1 = *(const float4*)(xp + 4);
      u16x8 tv;
      tv[0] = f2bf(v0.x); tv[1] = f2bf(v0.y); tv[2] = f2bf(v0.z); tv[3] = f2bf(v0.w);
      tv[4] = f2bf(v1.x); tv[5] = f2bf(v1.y); tv[6] = f2bf(v1.z); tv[7] = f2bf(v1.w);
      *(u16x8*)&Alds[rr][col] = tv;
    }
    __syncthreads();

    // ---- x-part MFMA (kt 0..7) while peers may still be finishing ----
    f32x4 acc0 = {bias_r, bias_r, bias_r, bias_r};
    f32x4 acc1 = acc0;
#pragma unroll
    for (int kt = 0; kt < 8; ++kt) {
      bf16x8 a0 = *(const bf16x8*)&Alds[l15][kt * 32 + lk * 8];
      bf16x8 a1 = *(const bf16x8*)&Alds[16 + l15][kt * 32 + lk * 8];
      acc0 = __builtin_amdgcn_mfma_f32_16x16x32_bf16(a0, Breg[kt], acc0, 0, 0, 0);
      acc1 = __builtin_amdgcn_mfma_f32_16x16x32_bf16(a1, Breg[kt], acc1, 0, 0, 0);
    }

    if (s > 0) {
      // ---- wait for h_{s-1}, stage it coherently ----
      group_wait(myFlags, s);
      const u16* hs = myH + ((s - 1) & 1) * (32 * 512);
      uint4 hv[8];
#pragma unroll
      for (int c = 0; c < 8; ++c) {
        int cc = tid + c * 256;
        int rr = cc >> 6;
        int col = (cc & 63) * 8;
        hv[c] = ld_coh_x4_issue(&hs[rr * 512 + col]);
      }
      wait_vm0();
      __builtin_amdgcn_sched_barrier(0);
#pragma unroll
      for (int c = 0; c < 8; ++c) {
        int cc = tid + c * 256;
        int rr = cc >> 6;
        int col = (cc & 63) * 8;
        *(uint4*)&Alds[rr][256 + col] = hv[c];
      }
      __syncthreads();

      // ---- h-part MFMA (kt 8..23) ----
#pragma unroll
      for (int kt = 8; kt < 24; ++kt) {
        bf16x8 a0 = *(const bf16x8*)&Alds[l15][kt * 32 + lk * 8];
        bf16x8 a1 = *(const bf16x8*)&Alds[16 + l15][kt * 32 + lk * 8];
        acc0 = __builtin_amdgcn_mfma_f32_16x16x32_bf16(a0, Breg[kt], acc0, 0, 0, 0);
        acc1 = __builtin_amdgcn_mfma_f32_16x16x32_bf16(a1, Breg[kt], acc1, 0, 0, 0);
      }
    }

    // ---- transpose gates, activations, write h to LDS gather tile ----
    {
#pragma unroll
      for (int r = 0; r < 4; ++r) zlds[wave][lk * 4 + r][l15] = acc0[r];
      asm volatile("s_waitcnt lgkmcnt(0)" ::: "memory");
      float4 gv = *(const float4*)&zlds[wave][l15][lk * 4];
      float iv = fsig(gv.x), fv = fsig(gv.y), gg = ftanhf(gv.z), ov = fsig(gv.w);
      c0 = fv * c0 + iv * gg;
      float hv0 = ov * ftanhf(c0);
      hlds[l15][wave * 4 + lk] = f2bf(hv0);
      if (s == 1023) latent[(size_t)(rowBase + l15) * 1024 + dir * 512 + uB] = hv0;
    }
    {
#pragma unroll
      for (int r = 0; r < 4; ++r) zlds[wave][lk * 4 + r][l15] = acc1[r];
      asm volatile("s_waitcnt lgkmcnt(0)" ::: "memory");
      float4 gv = *(const float4*)&zlds[wave][l15][lk * 4];
      float iv = fsig(gv.x), fv = fsig(gv.y), gg = ftanhf(gv.z), ov = fsig(gv.w);
      c1 = fv * c1 + iv * gg;
      float hv1 = ov * ftanhf(c1);
      hlds[16 + l15][wave * 4 + lk] = f2bf(hv1);
      if (s == 1023) latent[(size_t)(rowBase + 16 + l15) * 1024 + dir * 512 + uB] = hv1;
    }
    __syncthreads();

    // ---- coalesced coherent h store: 1 dword/thread, 32B runs ----
    if (s < 1023) {
      u16* hw = myH + (s & 1) * (32 * 512);
      int r = tid >> 3;
      int u2 = (tid & 7) * 2;
      uint32_t v = *(const uint32_t*)&hlds[r][u2];
      st_coh_dword(&hw[r * 512 + wgi * 16 + u2], v);
      wait_vm0();
    }
    __syncthreads();
    if (tid == 0 && s < 1023) flag_store(&myFlags[wgi], s + 1);
  }
}

// ---------------------------------------------------------------------------
// decoder: 8 groups x 16 rows, 32 WGs/group. xwd = latent@Wd+bd in regs.
// Dense fused on the staged h (wave0 of wgi<16).
// ---------------------------------------------------------------------------
__global__ __launch_bounds__(256, 1) void dec_kernel(
    const float* __restrict__ latent,
    const u16* __restrict__ udF, const u16* __restrict__ wdF, const u16* __restrict__ woF,
    const float* __restrict__ biasD, const float* __restrict__ bo,
    float* __restrict__ out, u16* __restrict__ hbuf, int* __restrict__ flags)
{
  const int bid = blockIdx.x;
  const int g   = bid & 7;
  const int wgi = bid >> 3;
  const int rowBase = g * 16;
  const int tid = threadIdx.x;
  const int lane = tid & 63;
  const int wave = tid >> 6;
  const int l15 = lane & 15;
  const int lk  = lane >> 4;

  __shared__ __attribute__((aligned(16))) u16   Llds[16][1032];
  __shared__ __attribute__((aligned(16))) u16   Alds[16][520];
  __shared__ __attribute__((aligned(16))) float zlds[4][16][20];
  __shared__ __attribute__((aligned(16))) u16   hlds[16][16];

#pragma unroll
  for (int c = 0; c < 8; ++c) {
    int cc = tid + c * 256;
    int rr = cc >> 7;
    int col = (cc & 127) * 8;
    const float* lp = latent + (size_t)(rowBase + rr) * 1024 + col;
    float4 v0 = *(const float4*)lp;
    float4 v1 = *(const float4*)(lp + 4);
    u16x8 tv;
    tv[0] = f2bf(v0.x); tv[1] = f2bf(v0.y); tv[2] = f2bf(v0.z); tv[3] = f2bf(v0.w);
    tv[4] = f2bf(v1.x); tv[5] = f2bf(v1.y); tv[6] = f2bf(v1.z); tv[7] = f2bf(v1.w);
    *(u16x8*)&Llds[rr][col] = tv;
  }
  __syncthreads();

  const float bd_r = biasD[wgi * 64 + wave * 16 + l15];
  f32x4 xwd = {bd_r, bd_r, bd_r, bd_r};
  {
    const u16* wf = wdF + (size_t)(wgi * 4 + wave) * 16384 + (size_t)lane * 8;
#pragma unroll
    for (int kt = 0; kt < 32; ++kt) {
      bf16x8 b = *(const bf16x8*)(wf + kt * 512);
      bf16x8 a = *(const bf16x8*)&Llds[l15][kt * 32 + lk * 8];
      xwd = __builtin_amdgcn_mfma_f32_16x16x32_bf16(a, b, xwd, 0, 0, 0);
    }
  }

  const u16* uf = udF + (size_t)(wgi * 4 + wave) * 8192 + (size_t)lane * 8;
  bf16x8 Bu[16];
#pragma unroll
  for (int kt = 0; kt < 16; ++kt) Bu[kt] = *(const bf16x8*)(uf + kt * 512);

  const bool doDense = (wgi < 16) && (wave == 0);
  bf16x8 Bo[16];
  if (doDense) {
    const u16* wof = woF + (size_t)wgi * 8192 + (size_t)lane * 8;
#pragma unroll
    for (int kt = 0; kt < 16; ++kt) Bo[kt] = *(const bf16x8*)(wof + kt * 512);
  }
  const float bo_r = (wgi < 16) ? bo[wgi * 16 + l15] : 0.f;

  u16* myH = hbuf + (size_t)g * (2 * 16 * 512);
  int* myFlags = flags + g * 32;
  float creg = 0.f;

  for (int t = 0; t < 1024; ++t) {
    if (t > 0) {
      group_wait(myFlags, t);
      const u16* hs = myH + ((t - 1) & 1) * (16 * 512);
      uint4 hv[4];
#pragma unroll
      for (int c = 0; c < 4; ++c) {
        int cc = tid + c * 256;
        int rr = cc >> 6;
        int col = (cc & 63) * 8;
        hv[c] = ld_coh_x4_issue(&hs[rr * 512 + col]);
      }
      wait_vm0();
      __builtin_amdgcn_sched_barrier(0);
#pragma unroll
      for (int c = 0; c < 4; ++c) {
        int cc = tid + c * 256;
        int rr = cc >> 6;
        int col = (cc & 63) * 8;
        *(uint4*)&Alds[rr][col] = hv[c];
      }
      __syncthreads();
      if (doDense) {
        f32x4 od = {bo_r, bo_r, bo_r, bo_r};
#pragma unroll
        for (int kt = 0; kt < 16; ++kt) {
          bf16x8 a = *(const bf16x8*)&Alds[l15][kt * 32 + lk * 8];
          od = __builtin_amdgcn_mfma_f32_16x16x32_bf16(a, Bo[kt], od, 0, 0, 0);
        }
#pragma unroll
        for (int r = 0; r < 4; ++r)
          out[((size_t)(rowBase + lk * 4 + r) * 1024 + (t - 1)) * 256 + wgi * 16 + l15] = od[r];
      }
    }

    f32x4 acc = xwd;
    if (t > 0) {
#pragma unroll
      for (int kt = 0; kt < 16; ++kt) {
        bf16x8 a = *(const bf16x8*)&Alds[l15][kt * 32 + lk * 8];
        acc = __builtin_amdgcn_mfma_f32_16x16x32_bf16(a, Bu[kt], acc, 0, 0, 0);
      }
    }

    {
#pragma unroll
      for (int r = 0; r < 4; ++r) zlds[wave][lk * 4 + r][l15] = acc[r];
      asm volatile("s_waitcnt lgkmcnt(0)" ::: "memory");
      float4 gv = *(const float4*)&zlds[wave][l15][lk * 4];
      float iv = fsig(gv.x), fv = fsig(gv.y), gg = ftanhf(gv.z), ov = fsig(gv.w);
      creg = fv * creg + iv * gg;
      float hv = ov * ftanhf(creg);
      hlds[l15][wave * 4 + lk] = f2bf(hv);
    }
    __syncthreads();

    if (tid < 128) {
      u16* hw = myH + (t & 1) * (16 * 512);
      int r = tid >> 3;
      int u2 = (tid & 7) * 2;
      uint32_t v = *(const uint32_t*)&hlds[r][u2];
      st_coh_dword(&hw[r * 512 + wgi * 16 + u2], v);
      wait_vm0();
    }
    __syncthreads();
    if (tid == 0) flag_store(&myFlags[wgi], t + 1);
  }

  // final output column (t = 1023)
  group_wait(myFlags, 1024);
  {
    const u16* hs = myH + (16 * 512);
    uint4 hv[4];
#pragma unroll
    for (int c = 0; c < 4; ++c) {
      int cc = tid + c * 256;
      int rr = cc >> 6;
      int col = (cc & 63) * 8;
      hv[c] = ld_coh_x4_issue(&hs[rr * 512 + col]);
    }
    wait_vm0();
    __builtin_amdgcn_sched_barrier(0);
#pragma unroll
    for (int c = 0; c < 4; ++c) {
      int cc = tid + c * 256;
      int rr = cc >> 6;
      int col = (cc & 63) * 8;
      *(uint4*)&Alds[rr][col] = hv[c];
    }
    __syncthreads();
    if (doDense) {
      f32x4 od = {bo_r, bo_r, bo_r, bo_r};
#pragma unroll
      for (int kt = 0; kt < 16; ++kt) {
        bf16x8 a = *(const bf16x8*)&Alds[l15][kt * 32 + lk * 8];
        od = __builtin_amdgcn_mfma_f32_16x16x32_bf16(a, Bo[kt], od, 0, 0, 0);
      }
#pragma unroll
      for (int r = 0; r < 4; ++r)
        out[((size_t)(rowBase + lk * 4 + r) * 1024 + 1023) * 256 + wgi * 16 + l15] = od[r];
    }
  }
}

// ---------------------------------------------------------------------------
extern "C" void kernel_launch(void* const* d_in, const int* in_sizes, int n_in,
                              void* d_out, int out_size, void* d_ws, size_t ws_size,
                              hipStream_t stream)
{
  const float* x  = (const float*)d_in[0];
  const float* Wf = (const float*)d_in[1];
  const float* Uf = (const float*)d_in[2];
  const float* bf = (const float*)d_in[3];
  const float* Wb = (const float*)d_in[4];
  const float* Ub = (const float*)d_in[5];
  const float* bb = (const float*)d_in[6];
  const float* Wd = (const float*)d_in[7];
  const float* Ud = (const float*)d_in[8];
  const float* bd = (const float*)d_in[9];
  const float* Wo = (const float*)d_in[10];
  const float* bo = (const float*)d_in[11];

  if (ws_size < 14182400) return;

  char* ws = (char*)d_ws;
  u16*  encF   = (u16*)(ws + 0);
  u16*  encB   = (u16*)(ws + 3145728);
  u16*  udF    = (u16*)(ws + 6291456);
  u16*  wdF    = (u16*)(ws + 8388608);
  u16*  woF    = (u16*)(ws + 12582912);
  float* biasF = (float*)(ws + 12845056);
  float* biasB = (float*)(ws + 12853248);
  float* biasD = (float*)(ws + 12861440);
  float* latent= (float*)(ws + 12869632);
  u16*  hbufE  = (u16*)(ws + 13393920);
  u16*  hbufD  = (u16*)(ws + 13918208);
  int*  flagsE = (int*)(ws + 14180352);
  int*  flagsD = (int*)(ws + 14181376);

  prep_kernel<<<256, 256, 0, stream>>>(Wf, Uf, bf, Wb, Ub, bb, Wd, Ud, bd, Wo,
                                       encF, encB, udF, wdF, woF,
                                       biasF, biasB, biasD, flagsE);
  enc_kernel<<<256, 256, 0, stream>>>(x, encF, encB, biasF, biasB, latent, hbufE, flagsE);
  dec_kernel<<<256, 256, 0, stream>>>(latent, udF, wdF, woF, biasD, bo,
                                      (float*)d_out, hbufD, flagsD);
}

// Round 3
// 5973.848 us; speedup vs baseline: 5.6993x; 1.0333x over previous
//
#include <hip/hip_runtime.h>
#include <stdint.h>

typedef unsigned short u16;
typedef short bf16x8 __attribute__((ext_vector_type(8)));
typedef float f32x4  __attribute__((ext_vector_type(4)));
typedef unsigned short u16x8 __attribute__((ext_vector_type(8)));

__device__ __forceinline__ u16 f2bf(float f) {
  uint32_t u = __float_as_uint(f);
  return (u16)((u + 0x7FFFu + ((u >> 16) & 1u)) >> 16);
}
__device__ __forceinline__ float fsig(float x) {
  x = fminf(fmaxf(x, -30.f), 30.f);
  return __builtin_amdgcn_rcpf(1.f + __builtin_amdgcn_exp2f(-1.44269504088896f * x));
}
__device__ __forceinline__ float ftanhf(float x) {
  x = fminf(fmaxf(x, -10.f), 10.f);
  float e = __builtin_amdgcn_exp2f(2.88539008177793f * x);
  return (e - 1.f) * __builtin_amdgcn_rcpf(e + 1.f);
}

// Coherent (cross-XCD) ops: sc0 sc1 => bypass L1/L2, serialize at MALL.
__device__ __forceinline__ int flag_load(const int* p) {
  int v;
  asm volatile("global_load_dword %0, %1, off sc0 sc1\n\ts_waitcnt vmcnt(0)"
               : "=v"(v) : "v"(p) : "memory");
  return v;
}
__device__ __forceinline__ void flag_store(int* p, int v) {
  asm volatile("global_store_dword %0, %1, off sc0 sc1" :: "v"(p), "v"(v) : "memory");
}
__device__ __forceinline__ uint4 ld_coh_x4_issue(const u16* p) {  // no waitcnt inside
  uint4 v;
  asm volatile("global_load_dwordx4 %0, %1, off sc0 sc1" : "=v"(v) : "v"(p) : "memory");
  return v;
}
__device__ __forceinline__ void st_coh_short(u16* p, uint32_t v) {
  asm volatile("global_store_short %0, %1, off sc0 sc1" :: "v"(p), "v"(v) : "memory");
}
__device__ __forceinline__ void wait_vm0() {
  asm volatile("s_waitcnt vmcnt(0)" ::: "memory");
}
// Weight-fragment load produced by volatile asm: compiler must keep it in VGPRs
// (cannot rematerialize), fixing the round-2 per-iteration reload.
__device__ __forceinline__ bf16x8 pin_frag(const u16* p) {
  uint4 v;
  asm volatile("global_load_dwordx4 %0, %1, off" : "=v"(v) : "v"(p));
  return __builtin_bit_cast(bf16x8, v);
}
__device__ __forceinline__ void poll_flag(const int* fp, int target) {
  int spins = 0;
  while (flag_load(fp) < target) {
    __builtin_amdgcn_s_sleep(1);
    if (++spins > 200000) break;   // bounded: broken sync -> wrong answer, not a hang
  }
}

// ---------------------------------------------------------------------------
// prep: f32 weights -> bf16 MFMA fragment layout, gate-permuted columns.
// n' = 4*unit + gate  =>  original column = gate*512 + unit.
// ---------------------------------------------------------------------------
__global__ void prep_kernel(const float* __restrict__ Wf, const float* __restrict__ Uf, const float* __restrict__ bf,
                            const float* __restrict__ Wb, const float* __restrict__ Ub, const float* __restrict__ bb,
                            const float* __restrict__ Wd, const float* __restrict__ Ud, const float* __restrict__ bd,
                            const float* __restrict__ Wo,
                            u16* __restrict__ encF, u16* __restrict__ encB,
                            u16* __restrict__ udF, u16* __restrict__ wdF, u16* __restrict__ woF,
                            float* __restrict__ biasF, float* __restrict__ biasB, float* __restrict__ biasD,
                            int* __restrict__ flagsAll)
{
  constexpr int NC_ENC = 128 * 24 * 64;
  constexpr int NC_UD  = 128 * 16 * 64;
  constexpr int NC_WD  = 128 * 32 * 64;
  constexpr int NC_WO  = 16 * 16 * 64;
  constexpr int B1 = 2 * NC_ENC;
  constexpr int B2 = B1 + NC_UD;
  constexpr int B3 = B2 + NC_WD;
  constexpr int B4 = B3 + NC_WO;
  constexpr int B5 = B4 + 768;
  constexpr int TOTAL = B5 + 64;

  for (int idx = blockIdx.x * 256 + threadIdx.x; idx < TOTAL; idx += gridDim.x * 256) {
    if (idx < B1) {
      int d = idx / NC_ENC;
      int r = idx - d * NC_ENC;
      int ntg = r / 1536;
      int rem = r - ntg * 1536;
      int kt = rem >> 6, lane = rem & 63;
      int np = ntg * 16 + (lane & 15);
      int col = (np & 3) * 512 + (np >> 2);
      int kb = kt * 32 + (lane >> 4) * 8;
      const float* W = d ? Wb : Wf;
      const float* U = d ? Ub : Uf;
      u16* dst = (d ? encB : encF) + (size_t)r * 8;
      if (kb < 256) {
        const float* s = W + (size_t)kb * 2048 + col;
#pragma unroll
        for (int e = 0; e < 8; ++e) dst[e] = f2bf(s[(size_t)e * 2048]);
      } else {
        const float* s = U + (size_t)(kb - 256) * 2048 + col;
#pragma unroll
        for (int e = 0; e < 8; ++e) dst[e] = f2bf(s[(size_t)e * 2048]);
      }
    } else if (idx < B2) {
      int r = idx - B1;
      int ntg = r / 1024;
      int rem = r - ntg * 1024;
      int kt = rem >> 6, lane = rem & 63;
      int np = ntg * 16 + (lane & 15);
      int col = (np & 3) * 512 + (np >> 2);
      int kb = kt * 32 + (lane >> 4) * 8;
      const float* s = Ud + (size_t)kb * 2048 + col;
      u16* dst = udF + (size_t)r * 8;
#pragma unroll
      for (int e = 0; e < 8; ++e) dst[e] = f2bf(s[(size_t)e * 2048]);
    } else if (idx < B3) {
      int r = idx - B2;
      int ntg = r / 2048;
      int rem = r - ntg * 2048;
      int kt = rem >> 6, lane = rem & 63;
      int np = ntg * 16 + (lane & 15);
      int col = (np & 3) * 512 + (np >> 2);
      int kb = kt * 32 + (lane >> 4) * 8;
      const float* s = Wd + (size_t)kb * 2048 + col;
      u16* dst = wdF + (size_t)r * 8;
#pragma unroll
      for (int e = 0; e < 8; ++e) dst[e] = f2bf(s[(size_t)e * 2048]);
    } else if (idx < B4) {
      int r = idx - B3;
      int nt = r / 1024;
      int rem = r - nt * 1024;
      int kt = rem >> 6, lane = rem & 63;
      int col = nt * 16 + (lane & 15);
      int kb = kt * 32 + (lane >> 4) * 8;
      const float* s = Wo + (size_t)kb * 256 + col;
      u16* dst = woF + (size_t)r * 8;
#pragma unroll
      for (int e = 0; e < 8; ++e) dst[e] = f2bf(s[(size_t)e * 256]);
    } else if (idx < B5) {
      int r = idx - B4;
      int which = r >> 8;
      int j0 = (r & 255) * 8;
      const float* src = (which == 0) ? bf : (which == 1) ? bb : bd;
      float* dstb = (which == 0) ? biasF : (which == 1) ? biasB : biasD;
#pragma unroll
      for (int e = 0; e < 8; ++e) {
        int np = j0 + e;
        dstb[np] = src[(np & 3) * 512 + (np >> 2)];
      }
    } else {
      int r = idx - B5;
#pragma unroll
      for (int e = 0; e < 8; ++e) flagsAll[r * 8 + e] = 0;
    }
  }
}

// ---------------------------------------------------------------------------
// encoder: 16 groups (dir = g>>3, rows (g&7)*16..+15), 16 WGs/group.
// WG = 256 thr; wave w owns 32 gate-cols (2 ntg tiles); weights pinned in
// 192 VGPRs. Per step: stage x + x-MFMA (off chain) -> per-thread flag poll ->
// coherent 16KB h load -> h-MFMA -> merged transpose -> act -> 2B h stores ->
// flag.
// ---------------------------------------------------------------------------
__global__ __launch_bounds__(256, 1) void enc_kernel(
    const float* __restrict__ x,
    const u16* __restrict__ encF, const u16* __restrict__ encB,
    const float* __restrict__ biasF, const float* __restrict__ biasB,
    float* __restrict__ latent, u16* __restrict__ hbuf, int* __restrict__ flags)
{
  const int bid = blockIdx.x;
  const int g   = bid & 15;
  const int wgi = bid >> 4;
  const int dir = g >> 3;
  const int rowBase = (g & 7) * 16;
  const int tid = threadIdx.x;
  const int lane = tid & 63;
  const int wave = tid >> 6;
  const int l15 = lane & 15;
  const int lk  = lane >> 4;

  __shared__ __attribute__((aligned(16))) u16   Alds[16][776];
  __shared__ __attribute__((aligned(16))) float zlds[4][2][16][20];

  const u16* wsrc = dir ? encB : encF;
  bf16x8 Breg[2][24];
#pragma unroll
  for (int n = 0; n < 2; ++n) {
    const int ntg = wgi * 8 + wave * 2 + n;
    const u16* fb = wsrc + (size_t)(ntg * 1536 + lane) * 8;
#pragma unroll
    for (int kt = 0; kt < 24; ++kt)
      Breg[n][kt] = pin_frag(fb + kt * 512);
  }
  wait_vm0();
  __builtin_amdgcn_sched_barrier(0);

  const float* bias = dir ? biasB : biasF;
  float bias_r[2];
  bias_r[0] = bias[(wgi * 8 + wave * 2 + 0) * 16 + l15];
  bias_r[1] = bias[(wgi * 8 + wave * 2 + 1) * 16 + l15];

  u16* myH = hbuf + (size_t)g * 16384;
  int* myFlags = flags + g * 16;
  const int* myPollFlag = &myFlags[(tid & 63) >> 2];  // each thread's 4 chunks come from one producer
  const int uW0 = wave * 8 + lk;                      // unit (q=0); q=1 adds 4

  float cc0 = 0.f, cc1 = 0.f;

  for (int s = 0; s < 1024; ++s) {
    const int t = dir ? (1023 - s) : s;

    { // stage x_t: thread -> row tid>>4, 16 floats at col (tid&15)*16
      const int rr = tid >> 4, cf = tid & 15;
      const float* xp = x + ((size_t)(rowBase + rr) * 1024 + t) * 256 + cf * 16;
      float4 v0 = *(const float4*)xp;
      float4 v1 = *(const float4*)(xp + 4);
      float4 v2 = *(const float4*)(xp + 8);
      float4 v3 = *(const float4*)(xp + 12);
      u16x8 a, b;
      a[0]=f2bf(v0.x); a[1]=f2bf(v0.y); a[2]=f2bf(v0.z); a[3]=f2bf(v0.w);
      a[4]=f2bf(v1.x); a[5]=f2bf(v1.y); a[6]=f2bf(v1.z); a[7]=f2bf(v1.w);
      b[0]=f2bf(v2.x); b[1]=f2bf(v2.y); b[2]=f2bf(v2.z); b[3]=f2bf(v2.w);
      b[4]=f2bf(v3.x); b[5]=f2bf(v3.y); b[6]=f2bf(v3.z); b[7]=f2bf(v3.w);
      *(u16x8*)&Alds[rr][cf * 16] = a;
      *(u16x8*)&Alds[rr][cf * 16 + 8] = b;
    }
    __syncthreads();

    f32x4 acc0 = {bias_r[0], bias_r[0], bias_r[0], bias_r[0]};
    f32x4 acc1 = {bias_r[1], bias_r[1], bias_r[1], bias_r[1]};
#pragma unroll
    for (int kt = 0; kt < 8; ++kt) {
      bf16x8 av = *(const bf16x8*)&Alds[l15][kt * 32 + lk * 8];
      acc0 = __builtin_amdgcn_mfma_f32_16x16x32_bf16(av, Breg[0][kt], acc0, 0, 0, 0);
      acc1 = __builtin_amdgcn_mfma_f32_16x16x32_bf16(av, Breg[1][kt], acc1, 0, 0, 0);
    }

    if (s > 0) {
      poll_flag(myPollFlag, s);
      const u16* hs = myH + ((s - 1) & 1) * 8192;
      uint4 hv[4];
#pragma unroll
      for (int c4 = 0; c4 < 4; ++c4) {
        const int ch = tid + c4 * 256;
        hv[c4] = ld_coh_x4_issue(&hs[(ch >> 6) * 512 + (ch & 63) * 8]);
      }
      wait_vm0();
      __builtin_amdgcn_sched_barrier(0);
#pragma unroll
      for (int c4 = 0; c4 < 4; ++c4) {
        const int ch = tid + c4 * 256;
        *(uint4*)&Alds[ch >> 6][256 + (ch & 63) * 8] = hv[c4];
      }
      __syncthreads();
#pragma unroll
      for (int kt = 8; kt < 24; ++kt) {
        bf16x8 av = *(const bf16x8*)&Alds[l15][kt * 32 + lk * 8];
        acc0 = __builtin_amdgcn_mfma_f32_16x16x32_bf16(av, Breg[0][kt], acc0, 0, 0, 0);
        acc1 = __builtin_amdgcn_mfma_f32_16x16x32_bf16(av, Breg[1][kt], acc1, 0, 0, 0);
      }
    }

    // merged transpose (one lgkm wait), activations
#pragma unroll
    for (int r = 0; r < 4; ++r) {
      zlds[wave][0][lk * 4 + r][l15] = acc0[r];
      zlds[wave][1][lk * 4 + r][l15] = acc1[r];
    }
    asm volatile("s_waitcnt lgkmcnt(0)" ::: "memory");
    float4 g0 = *(const float4*)&zlds[wave][0][l15][lk * 4];
    float4 g1 = *(const float4*)&zlds[wave][1][l15][lk * 4];
    float h0, h1;
    { float iv = fsig(g0.x), fv = fsig(g0.y), gg = ftanhf(g0.z), ov = fsig(g0.w);
      cc0 = fv * cc0 + iv * gg;  h0 = ov * ftanhf(cc0); }
    { float iv = fsig(g1.x), fv = fsig(g1.y), gg = ftanhf(g1.z), ov = fsig(g1.w);
      cc1 = fv * cc1 + iv * gg;  h1 = ov * ftanhf(cc1); }

    if (s < 1023) {
      u16* hw = myH + (s & 1) * 8192 + l15 * 512 + wgi * 32 + uW0;
      st_coh_short(hw,     (uint32_t)f2bf(h0));
      st_coh_short(hw + 4, (uint32_t)f2bf(h1));
      wait_vm0();
      __syncthreads();
      if (tid == 0) flag_store(&myFlags[wgi], s + 1);
    } else {
      float* lp = latent + (size_t)(rowBase + l15) * 1024 + dir * 512 + wgi * 32 + uW0;
      lp[0] = h0;
      lp[4] = h1;
    }
  }
}

// ---------------------------------------------------------------------------
// decoder: 8 groups x 16 rows, 16 WGs/group (128 WGs). xwd = latent@Wd+bd in
// regs (2 tiles); Bu pinned (128 VGPR). Dense (wave0, Bo pinned) runs AFTER
// the flag release so it overlaps the next wait; loop-end barrier guards Alds.
// ---------------------------------------------------------------------------
__global__ __launch_bounds__(256, 1) void dec_kernel(
    const float* __restrict__ latent,
    const u16* __restrict__ udF, const u16* __restrict__ wdF, const u16* __restrict__ woF,
    const float* __restrict__ biasD, const float* __restrict__ bo,
    float* __restrict__ out, u16* __restrict__ hbuf, int* __restrict__ flags)
{
  const int bid = blockIdx.x;      // 0..127
  const int g   = bid & 7;
  const int wgi = bid >> 3;        // 0..15
  const int rowBase = g * 16;
  const int tid = threadIdx.x;
  const int lane = tid & 63;
  const int wave = tid >> 6;
  const int l15 = lane & 15;
  const int lk  = lane >> 4;

  __shared__ __attribute__((aligned(16))) u16   Llds[16][1032];
  __shared__ __attribute__((aligned(16))) u16   Alds[16][520];
  __shared__ __attribute__((aligned(16))) float zlds[4][2][16][20];

  // stage latent rows (f32 -> bf16), one-time
#pragma unroll
  for (int c8 = 0; c8 < 8; ++c8) {
    const int idx = tid + c8 * 256;
    const int rr = idx >> 7, cf = idx & 127;
    const float* lp = latent + (size_t)(rowBase + rr) * 1024 + cf * 8;
    float4 v0 = *(const float4*)lp;
    float4 v1 = *(const float4*)(lp + 4);
    u16x8 tv;
    tv[0]=f2bf(v0.x); tv[1]=f2bf(v0.y); tv[2]=f2bf(v0.z); tv[3]=f2bf(v0.w);
    tv[4]=f2bf(v1.x); tv[5]=f2bf(v1.y); tv[6]=f2bf(v1.z); tv[7]=f2bf(v1.w);
    *(u16x8*)&Llds[rr][cf * 8] = tv;
  }
  __syncthreads();

  // xwd = latent @ Wd + bd (time-invariant), one-time
  f32x4 xwd[2];
#pragma unroll
  for (int n = 0; n < 2; ++n) {
    const int ntg = wgi * 8 + wave * 2 + n;
    const float br = biasD[ntg * 16 + l15];
    f32x4 xw = {br, br, br, br};
    const u16* wf = wdF + (size_t)(ntg * 2048 + lane) * 8;
#pragma unroll
    for (int kt = 0; kt < 32; ++kt) {
      bf16x8 b = *(const bf16x8*)(wf + kt * 512);
      bf16x8 a = *(const bf16x8*)&Llds[l15][kt * 32 + lk * 8];
      xw = __builtin_amdgcn_mfma_f32_16x16x32_bf16(a, b, xw, 0, 0, 0);
    }
    xwd[n] = xw;
  }

  bf16x8 Bu[2][16];
#pragma unroll
  for (int n = 0; n < 2; ++n) {
    const int ntg = wgi * 8 + wave * 2 + n;
    const u16* ub = udF + (size_t)(ntg * 1024 + lane) * 8;
#pragma unroll
    for (int kt = 0; kt < 16; ++kt)
      Bu[n][kt] = pin_frag(ub + kt * 512);
  }
  bf16x8 Bo[16];
  if (wave == 0) {
    const u16* ob = woF + (size_t)(wgi * 1024 + lane) * 8;
#pragma unroll
    for (int kt = 0; kt < 16; ++kt)
      Bo[kt] = pin_frag(ob + kt * 512);
  }
  wait_vm0();
  __builtin_amdgcn_sched_barrier(0);
  const float bo_r = bo[wgi * 16 + l15];

  u16* myH = hbuf + (size_t)g * 16384;
  int* myFlags = flags + g * 16;
  const int* myPollFlag = &myFlags[(tid & 63) >> 2];
  const int uW0 = wave * 8 + lk;

  float cc0 = 0.f, cc1 = 0.f;

  for (int t = 0; t < 1024; ++t) {
    f32x4 acc0 = xwd[0], acc1 = xwd[1];
    if (t > 0) {
      poll_flag(myPollFlag, t);
      const u16* hs = myH + ((t - 1) & 1) * 8192;
      uint4 hv[4];
#pragma unroll
      for (int c4 = 0; c4 < 4; ++c4) {
        const int ch = tid + c4 * 256;
        hv[c4] = ld_coh_x4_issue(&hs[(ch >> 6) * 512 + (ch & 63) * 8]);
      }
      wait_vm0();
      __builtin_amdgcn_sched_barrier(0);
#pragma unroll
      for (int c4 = 0; c4 < 4; ++c4) {
        const int ch = tid + c4 * 256;
        *(uint4*)&Alds[ch >> 6][(ch & 63) * 8] = hv[c4];
      }
      __syncthreads();
#pragma unroll
      for (int kt = 0; kt < 16; ++kt) {
        bf16x8 av = *(const bf16x8*)&Alds[l15][kt * 32 + lk * 8];
        acc0 = __builtin_amdgcn_mfma_f32_16x16x32_bf16(av, Bu[0][kt], acc0, 0, 0, 0);
        acc1 = __builtin_amdgcn_mfma_f32_16x16x32_bf16(av, Bu[1][kt], acc1, 0, 0, 0);
      }
    }

#pragma unroll
    for (int r = 0; r < 4; ++r) {
      zlds[wave][0][lk * 4 + r][l15] = acc0[r];
      zlds[wave][1][lk * 4 + r][l15] = acc1[r];
    }
    asm volatile("s_waitcnt lgkmcnt(0)" ::: "memory");
    float4 g0 = *(const float4*)&zlds[wave][0][l15][lk * 4];
    float4 g1 = *(const float4*)&zlds[wave][1][l15][lk * 4];
    float h0, h1;
    { float iv = fsig(g0.x), fv = fsig(g0.y), gg = ftanhf(g0.z), ov = fsig(g0.w);
      cc0 = fv * cc0 + iv * gg;  h0 = ov * ftanhf(cc0); }
    { float iv = fsig(g1.x), fv = fsig(g1.y), gg = ftanhf(g1.z), ov = fsig(g1.w);
      cc1 = fv * cc1 + iv * gg;  h1 = ov * ftanhf(cc1); }

    {
      u16* hw = myH + (t & 1) * 8192 + l15 * 512 + wgi * 32 + uW0;
      st_coh_short(hw,     (uint32_t)f2bf(h0));
      st_coh_short(hw + 4, (uint32_t)f2bf(h1));
      wait_vm0();
      __syncthreads();
      if (tid == 0) flag_store(&myFlags[wgi], t + 1);
    }

    // fused Dense for out[:, t-1, :] — off the recurrent chain (after release)
    if (t > 0 && wave == 0) {
      f32x4 od = {bo_r, bo_r, bo_r, bo_r};
#pragma unroll
      for (int kt = 0; kt < 16; ++kt) {
        bf16x8 a = *(const bf16x8*)&Alds[l15][kt * 32 + lk * 8];
        od = __builtin_amdgcn_mfma_f32_16x16x32_bf16(a, Bo[kt], od, 0, 0, 0);
      }
#pragma unroll
      for (int r = 0; r < 4; ++r)
        out[((size_t)(rowBase + lk * 4 + r) * 1024 + (t - 1)) * 256 + wgi * 16 + l15] = od[r];
    }
    __syncthreads();   // Alds stable until dense done
  }

  // out[:, 1023, :]
  poll_flag(myPollFlag, 1024);
  {
    const u16* hs = myH + 8192;   // slot 1 = h_1023
    uint4 hv[4];
#pragma unroll
    for (int c4 = 0; c4 < 4; ++c4) {
      const int ch = tid + c4 * 256;
      hv[c4] = ld_coh_x4_issue(&hs[(ch >> 6) * 512 + (ch & 63) * 8]);
    }
    wait_vm0();
    __builtin_amdgcn_sched_barrier(0);
#pragma unroll
    for (int c4 = 0; c4 < 4; ++c4) {
      const int ch = tid + c4 * 256;
      *(uint4*)&Alds[ch >> 6][(ch & 63) * 8] = hv[c4];
    }
    __syncthreads();
    if (wave == 0) {
      f32x4 od = {bo_r, bo_r, bo_r, bo_r};
#pragma unroll
      for (int kt = 0; kt < 16; ++kt) {
        bf16x8 a = *(const bf16x8*)&Alds[l15][kt * 32 + lk * 8];
        od = __builtin_amdgcn_mfma_f32_16x16x32_bf16(a, Bo[kt], od, 0, 0, 0);
      }
#pragma unroll
      for (int r = 0; r < 4; ++r)
        out[((size_t)(rowBase + lk * 4 + r) * 1024 + 1023) * 256 + wgi * 16 + l15] = od[r];
    }
  }
}

// ---------------------------------------------------------------------------
extern "C" void kernel_launch(void* const* d_in, const int* in_sizes, int n_in,
                              void* d_out, int out_size, void* d_ws, size_t ws_size,
                              hipStream_t stream)
{
  const float* x  = (const float*)d_in[0];
  const float* Wf = (const float*)d_in[1];
  const float* Uf = (const float*)d_in[2];
  const float* bf = (const float*)d_in[3];
  const float* Wb = (const float*)d_in[4];
  const float* Ub = (const float*)d_in[5];
  const float* bb = (const float*)d_in[6];
  const float* Wd = (const float*)d_in[7];
  const float* Ud = (const float*)d_in[8];
  const float* bd = (const float*)d_in[9];
  const float* Wo = (const float*)d_in[10];
  const float* bo = (const float*)d_in[11];

  if (ws_size < 14182400) return;

  char* ws = (char*)d_ws;
  u16*  encF   = (u16*)(ws + 0);
  u16*  encB   = (u16*)(ws + 3145728);
  u16*  udF    = (u16*)(ws + 6291456);
  u16*  wdF    = (u16*)(ws + 8388608);
  u16*  woF    = (u16*)(ws + 12582912);
  float* biasF = (float*)(ws + 12845056);
  float* biasB = (float*)(ws + 12853248);
  float* biasD = (float*)(ws + 12861440);
  float* latent= (float*)(ws + 12869632);
  u16*  hbufE  = (u16*)(ws + 13393920);   // 16 groups * 16384 u16 = 512KB
  u16*  hbufD  = (u16*)(ws + 13918208);   // 8 groups * 16384 u16 = 256KB
  int*  flagsE = (int*)(ws + 14180352);   // 256 ints
  int*  flagsD = (int*)(ws + 14181376);   // 128 ints (zeroed by prep, 512-int range)

  prep_kernel<<<256, 256, 0, stream>>>(Wf, Uf, bf, Wb, Ub, bb, Wd, Ud, bd, Wo,
                                       encF, encB, udF, wdF, woF,
                                       biasF, biasB, biasD, flagsE);
  enc_kernel<<<256, 256, 0, stream>>>(x, encF, encB, biasF, biasB, latent, hbufE, flagsE);
  dec_kernel<<<128, 256, 0, stream>>>(latent, udF, wdF, woF, biasD, bo,
                                      (float*)d_out, hbufD, flagsD);
}

// Round 8
// 5753.268 us; speedup vs baseline: 5.9178x; 1.0383x over previous
//
#include <hip/hip_runtime.h>
#include <stdint.h>

typedef unsigned short u16;
typedef short bf16x8 __attribute__((ext_vector_type(8)));
typedef float f32x4  __attribute__((ext_vector_type(4)));
typedef unsigned short u16x8 __attribute__((ext_vector_type(8)));

__device__ __forceinline__ u16 f2bf(float f) {
  uint32_t u = __float_as_uint(f);
  return (u16)((u + 0x7FFFu + ((u >> 16) & 1u)) >> 16);
}
__device__ __forceinline__ float fsig(float x) {
  x = fminf(fmaxf(x, -30.f), 30.f);
  return __builtin_amdgcn_rcpf(1.f + __builtin_amdgcn_exp2f(-1.44269504088896f * x));
}
__device__ __forceinline__ float ftanhf(float x) {
  x = fminf(fmaxf(x, -10.f), 10.f);
  float e = __builtin_amdgcn_exp2f(2.88539008177793f * x);
  return (e - 1.f) * __builtin_amdgcn_rcpf(e + 1.f);
}

// Coherent (cross-XCD) ops: sc0 sc1 => bypass L1/L2, serialize at MALL.
__device__ __forceinline__ int flag_load(const int* p) {
  int v;
  asm volatile("global_load_dword %0, %1, off sc0 sc1\n\ts_waitcnt vmcnt(0)"
               : "=v"(v) : "v"(p) : "memory");
  return v;
}
__device__ __forceinline__ void flag_store(int* p, int v) {
  asm volatile("global_store_dword %0, %1, off sc0 sc1" :: "v"(p), "v"(v) : "memory");
}
__device__ __forceinline__ uint4 ld_coh_x4(const u16* p) {   // issue only
  uint4 v;
  asm volatile("global_load_dwordx4 %0, %1, off sc0 sc1" : "=v"(v) : "v"(p) : "memory");
  return v;
}
__device__ __forceinline__ void st_coh_dword(u16* p, uint32_t v) {
  asm volatile("global_store_dword %0, %1, off sc0 sc1" :: "v"(p), "v"(v) : "memory");
}
__device__ __forceinline__ void wait_vm0() {
  asm volatile("s_waitcnt vmcnt(0)" ::: "memory");
}
// Weight-fragment load via volatile asm: result must stay resident (VGPR/AGPR).
__device__ __forceinline__ bf16x8 pin_frag(const u16* p) {
  uint4 v;
  asm volatile("global_load_dwordx4 %0, %1, off" : "=v"(v) : "v"(p));
  return __builtin_bit_cast(bf16x8, v);
}
__device__ __forceinline__ void poll_flag(const int* fp, int target) {
  int spins = 0;
  while (flag_load(fp) < target) {
    __builtin_amdgcn_s_sleep(1);
    if (++spins > 200000) break;   // bounded: broken sync -> wrong answer, not hang
  }
}

// ---------------------------------------------------------------------------
// prep: f32 weights -> bf16 MFMA fragment layout, gate-permuted columns;
// zeroes the 512 flag ints. n' = 4*unit + gate => original col = gate*512+unit.
// ---------------------------------------------------------------------------
__global__ void prep_kernel(const float* __restrict__ Wf, const float* __restrict__ Uf, const float* __restrict__ bf,
                            const float* __restrict__ Wb, const float* __restrict__ Ub, const float* __restrict__ bb,
                            const float* __restrict__ Wd, const float* __restrict__ Ud, const float* __restrict__ bd,
                            const float* __restrict__ Wo,
                            u16* __restrict__ encF, u16* __restrict__ encB,
                            u16* __restrict__ udF, u16* __restrict__ wdF, u16* __restrict__ woF,
                            float* __restrict__ biasF, float* __restrict__ biasB, float* __restrict__ biasD,
                            int* __restrict__ flagsAll)
{
  constexpr int NC_ENC = 128 * 24 * 64;
  constexpr int NC_UD  = 128 * 16 * 64;
  constexpr int NC_WD  = 128 * 32 * 64;
  constexpr int NC_WO  = 16 * 16 * 64;
  constexpr int B1 = 2 * NC_ENC;
  constexpr int B2 = B1 + NC_UD;
  constexpr int B3 = B2 + NC_WD;
  constexpr int B4 = B3 + NC_WO;
  constexpr int B5 = B4 + 768;
  constexpr int TOTAL = B5 + 64;

  for (int idx = blockIdx.x * 256 + threadIdx.x; idx < TOTAL; idx += gridDim.x * 256) {
    if (idx < B1) {
      int d = idx / NC_ENC;
      int r = idx - d * NC_ENC;
      int ntg = r / 1536;
      int rem = r - ntg * 1536;
      int kt = rem >> 6, lane = rem & 63;
      int np = ntg * 16 + (lane & 15);
      int col = (np & 3) * 512 + (np >> 2);
      int kb = kt * 32 + (lane >> 4) * 8;
      const float* W = d ? Wb : Wf;
      const float* U = d ? Ub : Uf;
      u16* dst = (d ? encB : encF) + (size_t)r * 8;
      if (kb < 256) {
        const float* s = W + (size_t)kb * 2048 + col;
#pragma unroll
        for (int e = 0; e < 8; ++e) dst[e] = f2bf(s[(size_t)e * 2048]);
      } else {
        const float* s = U + (size_t)(kb - 256) * 2048 + col;
#pragma unroll
        for (int e = 0; e < 8; ++e) dst[e] = f2bf(s[(size_t)e * 2048]);
      }
    } else if (idx < B2) {
      int r = idx - B1;
      int ntg = r / 1024;
      int rem = r - ntg * 1024;
      int kt = rem >> 6, lane = rem & 63;
      int np = ntg * 16 + (lane & 15);
      int col = (np & 3) * 512 + (np >> 2);
      int kb = kt * 32 + (lane >> 4) * 8;
      const float* s = Ud + (size_t)kb * 2048 + col;
      u16* dst = udF + (size_t)r * 8;
#pragma unroll
      for (int e = 0; e < 8; ++e) dst[e] = f2bf(s[(size_t)e * 2048]);
    } else if (idx < B3) {
      int r = idx - B2;
      int ntg = r / 2048;
      int rem = r - ntg * 2048;
      int kt = rem >> 6, lane = rem & 63;
      int np = ntg * 16 + (lane & 15);
      int col = (np & 3) * 512 + (np >> 2);
      int kb = kt * 32 + (lane >> 4) * 8;
      const float* s = Wd + (size_t)kb * 2048 + col;
      u16* dst = wdF + (size_t)r * 8;
#pragma unroll
      for (int e = 0; e < 8; ++e) dst[e] = f2bf(s[(size_t)e * 2048]);
    } else if (idx < B4) {
      int r = idx - B3;
      int nt = r / 1024;
      int rem = r - nt * 1024;
      int kt = rem >> 6, lane = rem & 63;
      int col = nt * 16 + (lane & 15);
      int kb = kt * 32 + (lane >> 4) * 8;
      const float* s = Wo + (size_t)kb * 256 + col;
      u16* dst = woF + (size_t)r * 8;
#pragma unroll
      for (int e = 0; e < 8; ++e) dst[e] = f2bf(s[(size_t)e * 256]);
    } else if (idx < B5) {
      int r = idx - B4;
      int which = r >> 8;
      int j0 = (r & 255) * 8;
      const float* src = (which == 0) ? bf : (which == 1) ? bb : bd;
      float* dstb = (which == 0) ? biasF : (which == 1) ? biasB : biasD;
#pragma unroll
      for (int e = 0; e < 8; ++e) {
        int np = j0 + e;
        dstb[np] = src[(np & 3) * 512 + (np >> 2)];
      }
    } else {
      int r = idx - B5;
#pragma unroll
      for (int e = 0; e < 8; ++e) flagsAll[r * 8 + e] = 0;
    }
  }
}

// ---------------------------------------------------------------------------
// h exchange layout (per group, per slot of 8192 u16):
//   chunk(b,row) = 8 u16 (units b*8..b*8+7, batch row) at u16 offset b*128+row*8.
//   Producer: wave w of WG wgi owns b = wgi*4+w -> 16 chunks, 256B contiguous.
//   Consumer thread tid: b = tid>>2, rows (tid&3)*4+k (k=0..3) at
//   hs, hs+8, hs+16, hs+24 (16B per row-chunk) -> all 4 chunks from producer
//   wgi = tid>>4, so the per-thread flag poll needs no barrier.
// ---------------------------------------------------------------------------

// encoder: 16 groups (dir=g>>3, rows (g&7)*16..+15), 16 WGs/group, 1 WG/CU.
__global__ __launch_bounds__(256, 1) void enc_kernel(
    const float* __restrict__ x,
    const u16* __restrict__ encF, const u16* __restrict__ encB,
    const float* __restrict__ biasF, const float* __restrict__ biasB,
    float* __restrict__ latent, u16* __restrict__ hbuf, int* __restrict__ flags)
{
  const int bid = blockIdx.x;
  const int g   = bid & 15;
  const int wgi = bid >> 4;
  const int dir = g >> 3;
  const int rowBase = (g & 7) * 16;
  const int tid = threadIdx.x;
  const int lane = tid & 63;
  const int wave = tid >> 6;
  const int l15 = lane & 15;
  const int lk  = lane >> 4;

  __shared__ __attribute__((aligned(16))) u16   xlds[2][16][264];
  __shared__ __attribute__((aligned(16))) u16   Alds[16][520];
  __shared__ __attribute__((aligned(16))) float zlds[4][2][16][20];
  __shared__ __attribute__((aligned(16))) u16   hlds[4][16][8];

  const u16* wsrc = dir ? encB : encF;
  bf16x8 Breg[2][24];
#pragma unroll
  for (int n = 0; n < 2; ++n) {
    const int ntg = wgi * 8 + wave * 2 + n;
    const u16* fb = wsrc + (size_t)(ntg * 1536 + lane) * 8;
#pragma unroll
    for (int kt = 0; kt < 24; ++kt)
      Breg[n][kt] = pin_frag(fb + kt * 512);
  }
  wait_vm0();
  __builtin_amdgcn_sched_barrier(0);

  const float* bias = dir ? biasB : biasF;
  float bias_r[2];
  bias_r[0] = bias[(wgi * 8 + wave * 2 + 0) * 16 + l15];
  bias_r[1] = bias[(wgi * 8 + wave * 2 + 1) * 16 + l15];

  u16* myH = hbuf + (size_t)g * 16384;
  int* myFlags = flags + g * 16;
  const int* myPollFlag = &myFlags[tid >> 4];   // producer of this thread's chunks
  const int xr = tid >> 4, xc = tid & 15;       // x staging assignment
  const int cb = tid >> 2;                      // consumer unit-block 0..63
  const int cr0 = (tid & 3) * 4;                // consumer first row

  // prologue: stage x_{t(0)} into xlds[0]
  {
    const int t0 = dir ? 1023 : 0;
    const float* xp = x + ((size_t)(rowBase + xr) * 1024 + t0) * 256 + xc * 16;
    float4 f0 = *(const float4*)xp;
    float4 f1 = *(const float4*)(xp + 4);
    float4 f2 = *(const float4*)(xp + 8);
    float4 f3 = *(const float4*)(xp + 12);
    u16x8 a, b;
    a[0]=f2bf(f0.x); a[1]=f2bf(f0.y); a[2]=f2bf(f0.z); a[3]=f2bf(f0.w);
    a[4]=f2bf(f1.x); a[5]=f2bf(f1.y); a[6]=f2bf(f1.z); a[7]=f2bf(f1.w);
    b[0]=f2bf(f2.x); b[1]=f2bf(f2.y); b[2]=f2bf(f2.z); b[3]=f2bf(f2.w);
    b[4]=f2bf(f3.x); b[5]=f2bf(f3.y); b[6]=f2bf(f3.z); b[7]=f2bf(f3.w);
    *(u16x8*)&xlds[0][xr][xc * 16] = a;
    *(u16x8*)&xlds[0][xr][xc * 16 + 8] = b;
  }
  __syncthreads();

  float cc0 = 0.f, cc1 = 0.f;

  for (int s = 0; s < 1024; ++s) {
    // ---- P1: x-part MFMA from xlds[s&1] ----
    f32x4 acc0 = {bias_r[0], bias_r[0], bias_r[0], bias_r[0]};
    f32x4 acc1 = {bias_r[1], bias_r[1], bias_r[1], bias_r[1]};
#pragma unroll
    for (int kt = 0; kt < 8; ++kt) {
      bf16x8 av = *(const bf16x8*)&xlds[s & 1][l15][kt * 32 + lk * 8];
      acc0 = __builtin_amdgcn_mfma_f32_16x16x32_bf16(av, Breg[0][kt], acc0, 0, 0, 0);
      acc1 = __builtin_amdgcn_mfma_f32_16x16x32_bf16(av, Breg[1][kt], acc1, 0, 0, 0);
    }

    // ---- P0: issue x loads for next step (latency hides under the poll) ----
    const int sn = (s + 1 < 1024) ? s + 1 : 1023;
    const int tn = dir ? (1023 - sn) : sn;
    const float* xp = x + ((size_t)(rowBase + xr) * 1024 + tn) * 256 + xc * 16;
    float4 f0 = *(const float4*)xp;
    float4 f1 = *(const float4*)(xp + 4);
    float4 f2 = *(const float4*)(xp + 8);
    float4 f3 = *(const float4*)(xp + 12);

    // ---- P2: flag poll + coherent h load + h-part MFMA ----
    if (s > 0) {
      poll_flag(myPollFlag, s);
      const u16* hs = myH + ((s - 1) & 1) * 8192 + cb * 128 + cr0 * 8;
      uint4 h0 = ld_coh_x4(hs);
      uint4 h1 = ld_coh_x4(hs + 8);
      uint4 h2 = ld_coh_x4(hs + 16);
      uint4 h3 = ld_coh_x4(hs + 24);
      wait_vm0();
      __builtin_amdgcn_sched_barrier(0);
      *(uint4*)&Alds[cr0][cb * 8]     = h0;
      *(uint4*)&Alds[cr0 + 1][cb * 8] = h1;
      *(uint4*)&Alds[cr0 + 2][cb * 8] = h2;
      *(uint4*)&Alds[cr0 + 3][cb * 8] = h3;
      __syncthreads();
#pragma unroll
      for (int kt = 0; kt < 16; ++kt) {
        bf16x8 av = *(const bf16x8*)&Alds[l15][kt * 32 + lk * 8];
        acc0 = __builtin_amdgcn_mfma_f32_16x16x32_bf16(av, Breg[0][kt + 8], acc0, 0, 0, 0);
        acc1 = __builtin_amdgcn_mfma_f32_16x16x32_bf16(av, Breg[1][kt + 8], acc1, 0, 0, 0);
      }
    }

    // ---- P3: transpose gates (wave-local LDS), activations ----
#pragma unroll
    for (int r = 0; r < 4; ++r) {
      zlds[wave][0][lk * 4 + r][l15] = acc0[r];
      zlds[wave][1][lk * 4 + r][l15] = acc1[r];
    }
    asm volatile("s_waitcnt lgkmcnt(0)" ::: "memory");
    float4 g0 = *(const float4*)&zlds[wave][0][l15][lk * 4];
    float4 g1 = *(const float4*)&zlds[wave][1][l15][lk * 4];
    float hv0, hv1;
    { float iv = fsig(g0.x), fv = fsig(g0.y), gg = ftanhf(g0.z), ov = fsig(g0.w);
      cc0 = fv * cc0 + iv * gg;  hv0 = ov * ftanhf(cc0); }
    { float iv = fsig(g1.x), fv = fsig(g1.y), gg = ftanhf(g1.z), ov = fsig(g1.w);
      cc1 = fv * cc1 + iv * gg;  hv1 = ov * ftanhf(cc1); }

    // ---- P4: wave-local gather + coalesced coherent stores (issue) ----
    if (s < 1023) {
      hlds[wave][l15][lk]     = f2bf(hv0);
      hlds[wave][l15][lk + 4] = f2bf(hv1);
      asm volatile("s_waitcnt lgkmcnt(0)" ::: "memory");
      if (lane < 16) {
        const uint4 c = *(const uint4*)&hlds[wave][lane][0];
        u16* hw = myH + (s & 1) * 8192 + (wgi * 4 + wave) * 128 + lane * 8;
        st_coh_dword(hw,     c.x);
        st_coh_dword(hw + 2, c.y);
        st_coh_dword(hw + 4, c.z);
        st_coh_dword(hw + 6, c.w);
      }
    } else {
      float* lp = latent + (size_t)(rowBase + l15) * 1024 + dir * 512 + wgi * 32 + wave * 8 + lk;
      lp[0] = hv0;
      lp[4] = hv1;
    }

    // ---- P5: convert + store x for next step (overlaps store drain) ----
    {
      u16x8 a, b;
      a[0]=f2bf(f0.x); a[1]=f2bf(f0.y); a[2]=f2bf(f0.z); a[3]=f2bf(f0.w);
      a[4]=f2bf(f1.x); a[5]=f2bf(f1.y); a[6]=f2bf(f1.z); a[7]=f2bf(f1.w);
      b[0]=f2bf(f2.x); b[1]=f2bf(f2.y); b[2]=f2bf(f2.z); b[3]=f2bf(f2.w);
      b[4]=f2bf(f3.x); b[5]=f2bf(f3.y); b[6]=f2bf(f3.z); b[7]=f2bf(f3.w);
      *(u16x8*)&xlds[(s + 1) & 1][xr][xc * 16] = a;
      *(u16x8*)&xlds[(s + 1) & 1][xr][xc * 16 + 8] = b;
    }

    // ---- release: drain stores, join, raise flag ----
    wait_vm0();
    __syncthreads();
    if (tid == 0 && s < 1023) flag_store(&myFlags[wgi], s + 1);
  }
}

// ---------------------------------------------------------------------------
// decoder: 8 groups x 16 rows, 16 WGs/group (128 WGs). xwd in regs; flag
// handoff; fused Dense (wave0) after release, off the recurrent chain.
// ---------------------------------------------------------------------------
__global__ __launch_bounds__(256, 1) void dec_kernel(
    const float* __restrict__ latent,
    const u16* __restrict__ udF, const u16* __restrict__ wdF, const u16* __restrict__ woF,
    const float* __restrict__ biasD, const float* __restrict__ bo,
    float* __restrict__ out, u16* __restrict__ hbuf, int* __restrict__ flags)
{
  const int bid = blockIdx.x;      // 0..127
  const int g   = bid & 7;
  const int wgi = bid >> 3;        // 0..15
  const int rowBase = g * 16;
  const int tid = threadIdx.x;
  const int lane = tid & 63;
  const int wave = tid >> 6;
  const int l15 = lane & 15;
  const int lk  = lane >> 4;

  __shared__ __attribute__((aligned(16))) u16   Llds[16][1032];
  __shared__ __attribute__((aligned(16))) u16   Alds[16][520];
  __shared__ __attribute__((aligned(16))) float zlds[4][2][16][20];
  __shared__ __attribute__((aligned(16))) u16   hlds[4][16][8];

#pragma unroll
  for (int c8 = 0; c8 < 8; ++c8) {
    const int idx = tid + c8 * 256;
    const int rr = idx >> 7, cf = idx & 127;
    const float* lp = latent + (size_t)(rowBase + rr) * 1024 + cf * 8;
    float4 v0 = *(const float4*)lp;
    float4 v1 = *(const float4*)(lp + 4);
    u16x8 tv;
    tv[0]=f2bf(v0.x); tv[1]=f2bf(v0.y); tv[2]=f2bf(v0.z); tv[3]=f2bf(v0.w);
    tv[4]=f2bf(v1.x); tv[5]=f2bf(v1.y); tv[6]=f2bf(v1.z); tv[7]=f2bf(v1.w);
    *(u16x8*)&Llds[rr][cf * 8] = tv;
  }
  __syncthreads();

  f32x4 xwd[2];
#pragma unroll
  for (int n = 0; n < 2; ++n) {
    const int ntg = wgi * 8 + wave * 2 + n;
    const float br = biasD[ntg * 16 + l15];
    f32x4 xw = {br, br, br, br};
    const u16* wf = wdF + (size_t)(ntg * 2048 + lane) * 8;
#pragma unroll
    for (int kt = 0; kt < 32; ++kt) {
      bf16x8 b = *(const bf16x8*)(wf + kt * 512);
      bf16x8 a = *(const bf16x8*)&Llds[l15][kt * 32 + lk * 8];
      xw = __builtin_amdgcn_mfma_f32_16x16x32_bf16(a, b, xw, 0, 0, 0);
    }
    xwd[n] = xw;
  }

  bf16x8 Bu[2][16];
#pragma unroll
  for (int n = 0; n < 2; ++n) {
    const int ntg = wgi * 8 + wave * 2 + n;
    const u16* ub = udF + (size_t)(ntg * 1024 + lane) * 8;
#pragma unroll
    for (int kt = 0; kt < 16; ++kt)
      Bu[n][kt] = pin_frag(ub + kt * 512);
  }
  bf16x8 Bo[16];
  if (wave == 0) {
    const u16* ob = woF + (size_t)(wgi * 1024 + lane) * 8;
#pragma unroll
    for (int kt = 0; kt < 16; ++kt)
      Bo[kt] = pin_frag(ob + kt * 512);
  }
  wait_vm0();
  __builtin_amdgcn_sched_barrier(0);
  const float bo_r = bo[wgi * 16 + l15];

  u16* myH = hbuf + (size_t)g * 16384;
  int* myFlags = flags + g * 16;
  const int* myPollFlag = &myFlags[tid >> 4];
  const int cb = tid >> 2;
  const int cr0 = (tid & 3) * 4;

  float cc0 = 0.f, cc1 = 0.f;

  for (int t = 0; t < 1024; ++t) {
    f32x4 acc0 = xwd[0], acc1 = xwd[1];

    if (t > 0) {
      poll_flag(myPollFlag, t);
      const u16* hs = myH + ((t - 1) & 1) * 8192 + cb * 128 + cr0 * 8;
      uint4 h0 = ld_coh_x4(hs);
      uint4 h1 = ld_coh_x4(hs + 8);
      uint4 h2 = ld_coh_x4(hs + 16);
      uint4 h3 = ld_coh_x4(hs + 24);
      wait_vm0();
      __builtin_amdgcn_sched_barrier(0);
      *(uint4*)&Alds[cr0][cb * 8]     = h0;
      *(uint4*)&Alds[cr0 + 1][cb * 8] = h1;
      *(uint4*)&Alds[cr0 + 2][cb * 8] = h2;
      *(uint4*)&Alds[cr0 + 3][cb * 8] = h3;
      __syncthreads();
#pragma unroll
      for (int kt = 0; kt < 16; ++kt) {
        bf16x8 av = *(const bf16x8*)&Alds[l15][kt * 32 + lk * 8];
        acc0 = __builtin_amdgcn_mfma_f32_16x16x32_bf16(av, Bu[0][kt], acc0, 0, 0, 0);
        acc1 = __builtin_amdgcn_mfma_f32_16x16x32_bf16(av, Bu[1][kt], acc1, 0, 0, 0);
      }
    }

#pragma unroll
    for (int r = 0; r < 4; ++r) {
      zlds[wave][0][lk * 4 + r][l15] = acc0[r];
      zlds[wave][1][lk * 4 + r][l15] = acc1[r];
    }
    asm volatile("s_waitcnt lgkmcnt(0)" ::: "memory");
    float4 g0 = *(const float4*)&zlds[wave][0][l15][lk * 4];
    float4 g1 = *(const float4*)&zlds[wave][1][l15][lk * 4];
    float hv0, hv1;
    { float iv = fsig(g0.x), fv = fsig(g0.y), gg = ftanhf(g0.z), ov = fsig(g0.w);
      cc0 = fv * cc0 + iv * gg;  hv0 = ov * ftanhf(cc0); }
    { float iv = fsig(g1.x), fv = fsig(g1.y), gg = ftanhf(g1.z), ov = fsig(g1.w);
      cc1 = fv * cc1 + iv * gg;  hv1 = ov * ftanhf(cc1); }

    // gather + coalesced coherent store + drain + flag (all steps, incl 1023)
    {
      hlds[wave][l15][lk]     = f2bf(hv0);
      hlds[wave][l15][lk + 4] = f2bf(hv1);
      asm volatile("s_waitcnt lgkmcnt(0)" ::: "memory");
      if (lane < 16) {
        const uint4 c = *(const uint4*)&hlds[wave][lane][0];
        u16* hw = myH + (t & 1) * 8192 + (wgi * 4 + wave) * 128 + lane * 8;
        st_coh_dword(hw,     c.x);
        st_coh_dword(hw + 2, c.y);
        st_coh_dword(hw + 4, c.z);
        st_coh_dword(hw + 6, c.w);
      }
      wait_vm0();
      __syncthreads();
      if (tid == 0) flag_store(&myFlags[wgi], t + 1);
    }

    // fused Dense for out[:, t-1, :] — after release, off the chain
    if (t > 0 && wave == 0) {
      f32x4 od = {bo_r, bo_r, bo_r, bo_r};
#pragma unroll
      for (int kt = 0; kt < 16; ++kt) {
        bf16x8 a = *(const bf16x8*)&Alds[l15][kt * 32 + lk * 8];
        od = __builtin_amdgcn_mfma_f32_16x16x32_bf16(a, Bo[kt], od, 0, 0, 0);
      }
#pragma unroll
      for (int r = 0; r < 4; ++r)
        out[((size_t)(rowBase + lk * 4 + r) * 1024 + (t - 1)) * 256 + wgi * 16 + l15] = od[r];
    }
    __syncthreads();   // Alds stable until dense done
  }

  // out[:, 1023, :]
  poll_flag(myPollFlag, 1024);
  {
    const u16* hs = myH + 8192 + cb * 128 + cr0 * 8;   // slot 1 = h_1023
    uint4 h0 = ld_coh_x4(hs);
    uint4 h1 = ld_coh_x4(hs + 8);
    uint4 h2 = ld_coh_x4(hs + 16);
    uint4 h3 = ld_coh_x4(hs + 24);
    wait_vm0();
    __builtin_amdgcn_sched_barrier(0);
    *(uint4*)&Alds[cr0][cb * 8]     = h0;
    *(uint4*)&Alds[cr0 + 1][cb * 8] = h1;
    *(uint4*)&Alds[cr0 + 2][cb * 8] = h2;
    *(uint4*)&Alds[cr0 + 3][cb * 8] = h3;
    __syncthreads();
    if (wave == 0) {
      f32x4 od = {bo_r, bo_r, bo_r, bo_r};
#pragma unroll
      for (int kt = 0; kt < 16; ++kt) {
        bf16x8 a = *(const bf16x8*)&Alds[l15][kt * 32 + lk * 8];
        od = __builtin_amdgcn_mfma_f32_16x16x32_bf16(a, Bo[kt], od, 0, 0, 0);
      }
#pragma unroll
      for (int r = 0; r < 4; ++r)
        out[((size_t)(rowBase + lk * 4 + r) * 1024 + 1023) * 256 + wgi * 16 + l15] = od[r];
    }
  }
}

// ---------------------------------------------------------------------------
extern "C" void kernel_launch(void* const* d_in, const int* in_sizes, int n_in,
                              void* d_out, int out_size, void* d_ws, size_t ws_size,
                              hipStream_t stream)
{
  const float* x  = (const float*)d_in[0];
  const float* Wf = (const float*)d_in[1];
  const float* Uf = (const float*)d_in[2];
  const float* bf = (const float*)d_in[3];
  const float* Wb = (const float*)d_in[4];
  const float* Ub = (const float*)d_in[5];
  const float* bb = (const float*)d_in[6];
  const float* Wd = (const float*)d_in[7];
  const float* Ud = (const float*)d_in[8];
  const float* bd = (const float*)d_in[9];
  const float* Wo = (const float*)d_in[10];
  const float* bo = (const float*)d_in[11];

  if (ws_size < 14182400) return;

  char* ws = (char*)d_ws;
  u16*  encF   = (u16*)(ws + 0);
  u16*  encB   = (u16*)(ws + 3145728);
  u16*  udF    = (u16*)(ws + 6291456);
  u16*  wdF    = (u16*)(ws + 8388608);
  u16*  woF    = (u16*)(ws + 12582912);
  float* biasF = (float*)(ws + 12845056);
  float* biasB = (float*)(ws + 12853248);
  float* biasD = (float*)(ws + 12861440);
  float* latent= (float*)(ws + 12869632);
  u16*  hbufE  = (u16*)(ws + 13393920);   // 16 groups * 16384 u16 = 512KB
  u16*  hbufD  = (u16*)(ws + 13918208);   // 8 groups * 16384 u16 = 256KB
  int*  flagsE = (int*)(ws + 14180352);   // 256 ints
  int*  flagsD = (int*)(ws + 14181376);   // 128 ints (prep zeroes 512-int range)

  prep_kernel<<<256, 256, 0, stream>>>(Wf, Uf, bf, Wb, Ub, bb, Wd, Ud, bd, Wo,
                                       encF, encB, udF, wdF, woF,
                                       biasF, biasB, biasD, flagsE);
  enc_kernel<<<256, 256, 0, stream>>>(x, encF, encB, biasF, biasB, latent, hbufE, flagsE);
  dec_kernel<<<128, 256, 0, stream>>>(latent, udF, wdF, woF, biasD, bo,
                                      (float*)d_out, hbufD, flagsD);
}